// Round 12
// baseline (151.780 us; speedup 1.0000x reference)
//
#include <hip/hip_runtime.h>
#include <stdint.h>

#define NX 2048
#define NQ 512
#define CDIM 1024
#define NH 16
#define DH 64

typedef __attribute__((ext_vector_type(8))) __bf16 bf16x8;
typedef __attribute__((ext_vector_type(4))) float f32x4;

__device__ __forceinline__ uint16_t f2bf(float f) {
  uint32_t i = __float_as_uint(f);
  uint32_t r = i + 0x7fffu + ((i >> 16) & 1u);
  return (uint16_t)(r >> 16);
}

#define GLD16(g, l)                                                            \
  __builtin_amdgcn_global_load_lds(                                            \
      (const __attribute__((address_space(1))) uint32_t*)(g),                  \
      (__attribute__((address_space(3))) uint32_t*)(l), 16, 0, 0)

// ---------------- fused casts: x->xh and cls->ch in one launch ----------------

__global__ __launch_bounds__(256) void cast2_bf16_kernel(
    const float* __restrict__ s0, uint16_t* __restrict__ d0, int n40,
    const float* __restrict__ s1, uint16_t* __restrict__ d1, int n41) {
  int i = blockIdx.x * blockDim.x + threadIdx.x;
  int stride = gridDim.x * blockDim.x;
  int ntot = n40 + n41;
  for (; i < ntot; i += stride) {
    if (i < n40) {
      float4 v = ((const float4*)s0)[i];
      ushort4 o;
      o.x = f2bf(v.x); o.y = f2bf(v.y); o.z = f2bf(v.z); o.w = f2bf(v.w);
      ((ushort4*)d0)[i] = o;
    } else {
      float4 v = ((const float4*)s1)[i - n40];
      ushort4 o;
      o.x = f2bf(v.x); o.y = f2bf(v.y); o.z = f2bf(v.z); o.w = f2bf(v.w);
      ((ushort4*)d1)[i - n40] = o;
    }
  }
}

// ---------------- fused weight transposes: w_kv, w_q, w_proj in one launch ----------------

__global__ __launch_bounds__(256) void transT_all_kernel(
    const float* __restrict__ w_kv, uint16_t* __restrict__ wkvT,
    const float* __restrict__ w_q, uint16_t* __restrict__ wqT,
    const float* __restrict__ w_proj, uint16_t* __restrict__ wpT) {
  const int z = blockIdx.z;
  const float* src;
  uint16_t* dst;
  int N;
  if (z == 0) { src = w_kv; dst = wkvT; N = 2048; }
  else if (z == 1) { src = w_q; dst = wqT; N = 1024; }
  else { src = w_proj; dst = wpT; N = 1024; }
  const int n0 = blockIdx.x * 64;
  if (n0 >= N) return;
  const int k0 = blockIdx.y * 64;
  __shared__ uint16_t tile[64][65];
  const int tid = threadIdx.x;
#pragma unroll
  for (int it = 0; it < 16; ++it) {
    int idx = it * 256 + tid;
    int r = idx >> 6, c = idx & 63;
    tile[r][c] = f2bf(src[(size_t)(k0 + r) * N + n0 + c]);
  }
  __syncthreads();
#pragma unroll
  for (int it = 0; it < 16; ++it) {
    int idx = it * 256 + tid;
    int r = idx >> 6, c = idx & 63;
    dst[(size_t)(n0 + r) * 1024 + k0 + c] = tile[c][r];
  }
}

// ---------------- aux_mm: q-proj (blocks 0..127) + gate GEMV (blocks 128..255) ----------------

__global__ __launch_bounds__(256) void aux_mm_kernel(
    const uint16_t* __restrict__ ch, const uint16_t* __restrict__ wqT,
    uint16_t* __restrict__ qbf, const uint16_t* __restrict__ xh,
    const float* __restrict__ wla, float* __restrict__ gv) {
  __shared__ __align__(16) uint16_t smem[16 * 1024];  // 32 KB union
  const int tid = threadIdx.x;
  const int wv = tid >> 6;
  const int lane = tid & 63;
  const int lr = lane & 15;
  const int lh = lane >> 4;

  if (blockIdx.x < 128) {
    uint16_t* sA = smem;
    uint16_t* sB = smem + 128 * 32;
    const int wm = wv >> 1, wn = wv & 1;
    const int rowBase = (blockIdx.x & 15) * 128;
    const int colBase = (blockIdx.x >> 4) * 128;

    f32x4 zero4 = {0.f, 0.f, 0.f, 0.f};
    f32x4 acc[4][4];
#pragma unroll
    for (int m = 0; m < 4; ++m)
#pragma unroll
      for (int n = 0; n < 4; ++n) acc[m][n] = zero4;

    for (int k0 = 0; k0 < 1024; k0 += 32) {
#pragma unroll
      for (int it = 0; it < 2; ++it) {
        int s = it * 256 + tid;
        int row = s >> 2, cc = s & 3;
        int sc = cc ^ ((row >> 1) & 3);
        GLD16(ch + (size_t)(rowBase + row) * 1024 + k0 + sc * 8,
              sA + ((size_t)it * 256 + wv * 64) * 8);
        GLD16(wqT + (size_t)(colBase + row) * 1024 + k0 + sc * 8,
              sB + ((size_t)it * 256 + wv * 64) * 8);
      }
      __syncthreads();
      bf16x8 af[4], bfr[4];
#pragma unroll
      for (int m = 0; m < 4; ++m) {
        int r = wm * 64 + m * 16 + lr;
        af[m] = *(const bf16x8*)&sA[r * 32 + ((lh ^ ((r >> 1) & 3)) << 3)];
      }
#pragma unroll
      for (int n = 0; n < 4; ++n) {
        int r = wn * 64 + n * 16 + lr;
        bfr[n] = *(const bf16x8*)&sB[r * 32 + ((lh ^ ((r >> 1) & 3)) << 3)];
      }
#pragma unroll
      for (int m = 0; m < 4; ++m)
#pragma unroll
        for (int n = 0; n < 4; ++n)
          acc[m][n] = __builtin_amdgcn_mfma_f32_16x16x32_bf16(af[m], bfr[n],
                                                              acc[m][n], 0, 0, 0);
      __syncthreads();
    }

#pragma unroll
    for (int m = 0; m < 4; ++m) {
      int gr0 = rowBase + wm * 64 + m * 16 + lh * 4;
      int b = gr0 >> 9, nq0 = gr0 & 511;
#pragma unroll
      for (int n = 0; n < 4; ++n) {
        int gc = colBase + wn * 64 + n * 16 + lr;
        int hh = gc >> 6, d = gc & 63;
        size_t base = (((size_t)b * NH + hh) * NQ + nq0) * DH + d;
#pragma unroll
        for (int j = 0; j < 4; ++j)
          qbf[base + (size_t)j * DH] = f2bf(acc[m][n][j] * 0.125f);
      }
    }
  } else {
    uint16_t* sW = smem;
#pragma unroll
    for (int it = 0; it < 64; ++it) {
      int i = it * 256 + tid;
      int c = i >> 4, h = i & 15;
      sW[h * 1024 + (((c >> 3) ^ (h & 7)) << 3) + (c & 7)] = f2bf(wla[i]);
    }
    __syncthreads();

    const int rb = (blockIdx.x - 128) * 64 + wv * 16;
    f32x4 acc = {0.f, 0.f, 0.f, 0.f};
    for (int t = 0; t < 32; ++t) {
      bf16x8 af = *(const bf16x8*)&xh[(size_t)(rb + lr) * 1024 + t * 32 + lh * 8];
      bf16x8 bf = *(const bf16x8*)&sW[lr * 1024 + (((t * 4 + lh) ^ (lr & 7)) << 3)];
      acc = __builtin_amdgcn_mfma_f32_16x16x32_bf16(af, bf, acc, 0, 0, 0);
    }
    int nxg = rb + lh * 4;
    int b = nxg >> 11, nx = nxg & 2047;
    float4 st = {acc[0], acc[1], acc[2], acc[3]};
    *(float4*)&gv[((size_t)b * NH + lr) * NX + nx] = st;
  }
}

// ---------------- 8-phase 256x256 GEMM for x@w_kv (round-8 proven, 256 blocks = 1/CU) ----------------

__global__ __launch_bounds__(512, 2) void gemm_kv8(
    const uint16_t* __restrict__ A, const uint16_t* __restrict__ BT,
    uint16_t* __restrict__ outK, uint16_t* __restrict__ outV) {
  __shared__ __align__(16) uint16_t lds[65536];  // [buf][A|B][256][64]

  const int tid = threadIdx.x;
  const int wid = tid >> 6;
  const int lane = tid & 63;
  const int lr = lane & 15;
  const int lh = lane >> 4;
  const int wm = wid >> 2;
  const int wn = wid & 3;
  const int rowBase = blockIdx.x * 256;
  const int colBase = blockIdx.y * 256;

  f32x4 acc[8][4];
#pragma unroll
  for (int m = 0; m < 8; ++m)
#pragma unroll
    for (int n = 0; n < 4; ++n) acc[m][n] = (f32x4){0.f, 0.f, 0.f, 0.f};

  auto stageB = [&](int T, int h) {
    const uint16_t* srcp = BT + (size_t)(colBase + h * 128) * 1024 + T * 64;
    uint16_t* dst = lds + ((T & 1) * 32768 + 16384 + h * 8192);
#pragma unroll
    for (int it = 0; it < 2; ++it) {
      int s = it * 512 + tid;
      int row = s >> 3, cc = s & 7;
      int sc = cc ^ (row & 7);
      GLD16(srcp + (size_t)row * 1024 + sc * 8,
            dst + ((size_t)it * 512 + wid * 64) * 8);
    }
  };
  auto stageA012 = [&](int T) {
    const uint16_t* srcp = A + (size_t)rowBase * 1024 + T * 64;
    uint16_t* dstbase = lds + (T & 1) * 32768;
    int r64 = tid >> 3, cc = tid & 7;
#pragma unroll
    for (int st = 0; st < 3; ++st) {
      int rloc = (r64 < 32) ? (st * 32 + r64) : (96 + st * 32 + r64);
      int sc = cc ^ (rloc & 7);
      int wrow = (wid < 4) ? (st * 32 + wid * 8) : (128 + st * 32 + (wid - 4) * 8);
      GLD16(srcp + (size_t)rloc * 1024 + sc * 8, dstbase + (size_t)wrow * 64);
    }
  };
  auto stageA3 = [&](int T) {
    const uint16_t* srcp = A + (size_t)rowBase * 1024 + T * 64;
    uint16_t* dstbase = lds + (T & 1) * 32768;
    int r64 = tid >> 3, cc = tid & 7;
    int rloc = (r64 < 32) ? (96 + r64) : (192 + r64);
    int sc = cc ^ (rloc & 7);
    int wrow = (wid < 4) ? (96 + wid * 8) : (224 + (wid - 4) * 8);
    GLD16(srcp + (size_t)rloc * 1024 + sc * 8, dstbase + (size_t)wrow * 64);
  };

  auto rdA = [&](int p, int m, int kk) -> bf16x8 {
    int r = wm * 128 + m * 16 + lr;
    return *(const bf16x8*)&lds[p * 32768 + r * 64 +
                                (((kk * 4 + lh) ^ (r & 7)) << 3)];
  };
  auto rdB = [&](int p, int n, int kk) -> bf16x8 {
    int r = wn * 64 + n * 16 + lr;
    return *(const bf16x8*)&lds[p * 32768 + 16384 + r * 64 +
                                (((kk * 4 + lh) ^ (r & 7)) << 3)];
  };

  auto tile4 = [&](int t, bool last) {
    const int p = t & 1;
    bf16x8 b[4][2], a0[2], a1[2];
#pragma unroll
    for (int q = 0; q < 4; ++q) {
      if (q == 0) {
#pragma unroll
        for (int n = 0; n < 4; ++n)
#pragma unroll
          for (int kk = 0; kk < 2; ++kk) b[n][kk] = rdB(p, n, kk);
      }
#pragma unroll
      for (int kk = 0; kk < 2; ++kk) {
        a0[kk] = rdA(p, 2 * q, kk);
        a1[kk] = rdA(p, 2 * q + 1, kk);
      }
      if (q == 0) {
        stageA3(t + 1);
      } else if (q == 1) {
        if (!last) stageB(t + 2, 0);
      } else if (q == 2) {
        if (!last) stageB(t + 2, 1);
      } else {
        if (!last) stageA012(t + 2);
        if (last)
          asm volatile("s_waitcnt vmcnt(0)" ::: "memory");
        else
          asm volatile("s_waitcnt vmcnt(7)" ::: "memory");
      }
      __builtin_amdgcn_s_barrier();
      asm volatile("s_waitcnt lgkmcnt(0)" ::: "memory");
      __builtin_amdgcn_sched_barrier(0);
      __builtin_amdgcn_s_setprio(1);
#pragma unroll
      for (int n = 0; n < 4; ++n)
#pragma unroll
        for (int kk = 0; kk < 2; ++kk) {
          acc[2 * q][n] = __builtin_amdgcn_mfma_f32_16x16x32_bf16(
              a0[kk], b[n][kk], acc[2 * q][n], 0, 0, 0);
          acc[2 * q + 1][n] = __builtin_amdgcn_mfma_f32_16x16x32_bf16(
              a1[kk], b[n][kk], acc[2 * q + 1][n], 0, 0, 0);
        }
      __builtin_amdgcn_s_setprio(0);
      __builtin_amdgcn_s_barrier();
      asm volatile("" ::: "memory");
    }
  };

  auto tileEpi = [&](int t) {
    const int p = t & 1;
    bf16x8 b[4][2], a0[2], a1[2];
#pragma unroll
    for (int n = 0; n < 4; ++n)
#pragma unroll
      for (int kk = 0; kk < 2; ++kk) b[n][kk] = rdB(p, n, kk);
#pragma unroll
    for (int q = 0; q < 4; ++q) {
#pragma unroll
      for (int kk = 0; kk < 2; ++kk) {
        a0[kk] = rdA(p, 2 * q, kk);
        a1[kk] = rdA(p, 2 * q + 1, kk);
      }
#pragma unroll
      for (int n = 0; n < 4; ++n)
#pragma unroll
        for (int kk = 0; kk < 2; ++kk) {
          acc[2 * q][n] = __builtin_amdgcn_mfma_f32_16x16x32_bf16(
              a0[kk], b[n][kk], acc[2 * q][n], 0, 0, 0);
          acc[2 * q + 1][n] = __builtin_amdgcn_mfma_f32_16x16x32_bf16(
              a1[kk], b[n][kk], acc[2 * q + 1][n], 0, 0, 0);
        }
    }
  };

  stageB(0, 0); stageB(0, 1); stageA012(0); stageA3(0);
  stageB(1, 0); stageB(1, 1); stageA012(1);
  asm volatile("s_waitcnt vmcnt(7)" ::: "memory");
  __builtin_amdgcn_s_barrier();

  for (int t = 0; t < 14; ++t) tile4(t, false);
  tile4(14, true);
  tileEpi(15);

#pragma unroll
  for (int m = 0; m < 8; ++m) {
    int gr0 = rowBase + wm * 128 + m * 16 + lh * 4;
    int b_ = gr0 >> 11, nx0 = gr0 & 2047;
#pragma unroll
    for (int n = 0; n < 4; ++n) {
      int gc = colBase + wn * 64 + n * 16 + lr;
      if (gc < 1024) {
        int hh = gc >> 6, d = gc & 63;
        size_t base = (((size_t)b_ * NH + hh) * NX + nx0) * DH + d;
#pragma unroll
        for (int j = 0; j < 4; ++j)
          outK[base + (size_t)j * DH] = f2bf(acc[m][n][j]);
      } else {
        int c2 = gc - 1024;
        int hh = c2 >> 6, d = c2 & 63;
        ushort4 pv;
        pv.x = f2bf(acc[m][n][0]);
        pv.y = f2bf(acc[m][n][1]);
        pv.z = f2bf(acc[m][n][2]);
        pv.w = f2bf(acc[m][n][3]);
        *(ushort4*)&outV[(((size_t)b_ * NH + hh) * DH + d) * NX + nx0] = pv;
      }
    }
  }
}

// ---------------- 128x128 GEMM: ctx@w_proj + bias -> out fp32 ----------------

__global__ __launch_bounds__(256) void gemm_proj(
    const uint16_t* __restrict__ A, const uint16_t* __restrict__ BT,
    float* __restrict__ outF, const float* __restrict__ bias) {
  constexpr int K = 1024;
  __shared__ __align__(16) uint16_t sA[128 * 32];
  __shared__ __align__(16) uint16_t sB[128 * 32];

  const int tid = threadIdx.x;
  const int wv = tid >> 6;
  const int lane = tid & 63;
  const int lr = lane & 15;
  const int lh = lane >> 4;
  const int wm = wv >> 1, wn = wv & 1;
  const int rowBase = blockIdx.x * 128;
  const int colBase = blockIdx.y * 128;

  f32x4 zero4 = {0.f, 0.f, 0.f, 0.f};
  f32x4 acc[4][4];
#pragma unroll
  for (int m = 0; m < 4; ++m)
#pragma unroll
    for (int n = 0; n < 4; ++n) acc[m][n] = zero4;

  for (int k0 = 0; k0 < K; k0 += 32) {
#pragma unroll
    for (int it = 0; it < 2; ++it) {
      int s = it * 256 + tid;
      int row = s >> 2, cc = s & 3;
      int sc = cc ^ ((row >> 1) & 3);
      GLD16(A + (size_t)(rowBase + row) * K + k0 + sc * 8,
            sA + ((size_t)it * 256 + wv * 64) * 8);
      GLD16(BT + (size_t)(colBase + row) * K + k0 + sc * 8,
            sB + ((size_t)it * 256 + wv * 64) * 8);
    }
    __syncthreads();
    bf16x8 af[4], bfr[4];
#pragma unroll
    for (int m = 0; m < 4; ++m) {
      int r = wm * 64 + m * 16 + lr;
      af[m] = *(const bf16x8*)&sA[r * 32 + ((lh ^ ((r >> 1) & 3)) << 3)];
    }
#pragma unroll
    for (int n = 0; n < 4; ++n) {
      int r = wn * 64 + n * 16 + lr;
      bfr[n] = *(const bf16x8*)&sB[r * 32 + ((lh ^ ((r >> 1) & 3)) << 3)];
    }
#pragma unroll
    for (int m = 0; m < 4; ++m)
#pragma unroll
      for (int n = 0; n < 4; ++n)
        acc[m][n] = __builtin_amdgcn_mfma_f32_16x16x32_bf16(af[m], bfr[n],
                                                            acc[m][n], 0, 0, 0);
    __syncthreads();
  }

#pragma unroll
  for (int m = 0; m < 4; ++m) {
    int gr0 = rowBase + wm * 64 + m * 16 + lh * 4;
#pragma unroll
    for (int n = 0; n < 4; ++n) {
      int gc = colBase + wn * 64 + n * 16 + lr;
      float bi = bias[gc];
#pragma unroll
      for (int j = 0; j < 4; ++j)
        outF[(size_t)(gr0 + j) * 1024 + gc] = acc[m][n][j] + bi;
    }
  }
}

// ---------------- gate reduce ----------------

__global__ __launch_bounds__(256) void gate2_kernel(
    const float* __restrict__ gv, float* __restrict__ gate) {
  const int bh = blockIdx.x;
  const int tid = threadIdx.x;
  const float* p = gv + (size_t)bh * NX;
  float s = 0.f, mx = -1e30f;
  for (int i = tid; i < NX; i += 256) {
    float v = p[i];
    s += v;
    mx = fmaxf(mx, v);
  }
#pragma unroll
  for (int off = 1; off < 64; off <<= 1) {
    s += __shfl_xor(s, off, 64);
    mx = fmaxf(mx, __shfl_xor(mx, off, 64));
  }
  __shared__ float ss[4], sm[4];
  int wv = tid >> 6, lane = tid & 63;
  if (lane == 0) { ss[wv] = s; sm[wv] = mx; }
  __syncthreads();
  if (tid == 0) {
    float S = ss[0] + ss[1] + ss[2] + ss[3];
    float M = fmaxf(fmaxf(sm[0], sm[1]), fmaxf(sm[2], sm[3]));
    gate[bh] = 0.5f * (S / (float)NX) + 0.5f * M;
  }
}

// ---------------- column sum of V ----------------

__global__ __launch_bounds__(256) void vcolsum_kernel(
    const uint16_t* __restrict__ VT, float* __restrict__ vcs) {
  const int bh = blockIdx.x;
  const int wv = threadIdx.x >> 6, lane = threadIdx.x & 63;
#pragma unroll
  for (int dd = 0; dd < 4; ++dd) {
    int d = blockIdx.y * 16 + dd * 4 + wv;
    const uint16_t* row = VT + ((size_t)bh * DH + d) * NX;
    float s = 0.f;
#pragma unroll
    for (int i = 0; i < 4; ++i) {
      bf16x8 v = *(const bf16x8*)&row[(i * 64 + lane) * 8];
#pragma unroll
      for (int j = 0; j < 8; ++j) s += (float)v[j];
    }
#pragma unroll
    for (int off = 1; off < 64; off <<= 1) s += __shfl_xor(s, off, 64);
    if (lane == 0) vcs[bh * DH + d] = s;
  }
}

// ---------------- attention part: K-split flash (no-max => pure sums, exact split) ----------------
// grid (64 bh, 8 q-blocks, 2 key-halves); z owns kt in [8z, 8z+8).
// Body = round-8 proven kernel; writes partial u (fp32) and partial l.
// 1024 blocks, 48 KB LDS -> 3 blocks/CU co-resident (12 waves/CU vs 8).

__global__ __launch_bounds__(256) void attn_part_kernel(
    const uint16_t* __restrict__ Q, const uint16_t* __restrict__ K,
    const uint16_t* __restrict__ VT, float* __restrict__ up,
    float* __restrict__ lpart) {
  __shared__ __align__(16) uint16_t sK[128 * 64];
  __shared__ __align__(16) uint16_t sV[64 * 128];
  __shared__ __align__(16) __bf16 sPe[64 * 128];

  const int tid = threadIdx.x;
  const int wv = tid >> 6;
  const int lane = tid & 63;
  const int lr = lane & 15;
  const int lh = lane >> 4;
  const int bh = blockIdx.x;
  const int q0 = blockIdx.y * 64;
  const int z = blockIdx.z;

  const uint16_t* Qb = Q + ((size_t)bh * NQ + q0) * DH;
  const uint16_t* Kb = K + (size_t)bh * NX * DH;
  const uint16_t* Vb = VT + (size_t)bh * DH * NX;

  bf16x8 qa[2];
#pragma unroll
  for (int kk = 0; kk < 2; ++kk)
    qa[kk] = *(const bf16x8*)&Qb[(wv * 16 + lr) * DH + kk * 32 + lh * 8];

  float lp[4] = {0.f, 0.f, 0.f, 0.f};
  f32x4 zero4 = {0.f, 0.f, 0.f, 0.f};
  f32x4 accp[4];
#pragma unroll
  for (int d = 0; d < 4; ++d) accp[d] = zero4;

  for (int kt = z * 8; kt < z * 8 + 8; ++kt) {
#pragma unroll
    for (int it = 0; it < 4; ++it) {
      int s = it * 256 + tid;
      int row = s >> 3, cc = s & 7;
      int sc = cc ^ (row & 7);
      GLD16(Kb + (size_t)(kt * 128 + row) * DH + sc * 8,
            sK + ((size_t)it * 256 + wv * 64) * 8);
    }
#pragma unroll
    for (int it = 0; it < 4; ++it) {
      int s = it * 256 + tid;
      int row = s >> 4, cc = s & 15;
      int sc = cc ^ (row & 15);
      GLD16(Vb + (size_t)row * NX + kt * 128 + sc * 8,
            sV + ((size_t)it * 256 + wv * 64) * 8);
    }
    __syncthreads();
#pragma unroll
    for (int n = 0; n < 8; ++n) {
      f32x4 a4 = {0.f, 0.f, 0.f, 0.f};
      int r = n * 16 + lr;
#pragma unroll
      for (int kk = 0; kk < 2; ++kk) {
        bf16x8 kb = *(const bf16x8*)&sK[r * 64 + (((kk * 4 + lh) ^ (r & 7)) << 3)];
        a4 = __builtin_amdgcn_mfma_f32_16x16x32_bf16(qa[kk], kb, a4, 0, 0, 0);
      }
#pragma unroll
      for (int j = 0; j < 4; ++j) {
        float e = __expf(a4[j]);
        lp[j] += e;
        int qr = wv * 16 + lh * 4 + j;
        int key = n * 16 + lr;
        int idx = qr * 128 + ((((key >> 3) ^ (qr & 15))) << 3) + (key & 7);
        sPe[idx] = (__bf16)e;
      }
    }
    __syncthreads();
    const int prow = wv * 16 + lr;
#pragma unroll
    for (int kk = 0; kk < 4; ++kk) {
      int pidx = prow * 128 + (((kk * 4 + lh) ^ (prow & 15)) << 3);
      bf16x8 pe = *(const bf16x8*)&sPe[pidx];
#pragma unroll
      for (int df = 0; df < 4; ++df) {
        int vr = df * 16 + lr;
        bf16x8 vb = *(const bf16x8*)&sV[vr * 128 + (((kk * 4 + lh) ^ (vr & 15)) << 3)];
        accp[df] = __builtin_amdgcn_mfma_f32_16x16x32_bf16(pe, vb, accp[df], 0, 0, 0);
      }
    }
    __syncthreads();
  }
#pragma unroll
  for (int off = 1; off < 16; off <<= 1)
#pragma unroll
    for (int j = 0; j < 4; ++j) lp[j] += __shfl_xor(lp[j], off, 64);

  const size_t plane = (size_t)(z * 64 + bh) * NQ;
#pragma unroll
  for (int df = 0; df < 4; ++df) {
    int d = df * 16 + lr;
#pragma unroll
    for (int j = 0; j < 4; ++j) {
      int qr = q0 + wv * 16 + lh * 4 + j;
      up[(plane + qr) * DH + d] = accp[df][j];
    }
  }
  if (lr == 0) {
#pragma unroll
    for (int j = 0; j < 4; ++j)
      lpart[plane + q0 + wv * 16 + lh * 4 + j] = lp[j];
  }
}

// ---------------- attention combine: ctx = c1*cv + c2*(u0+u1)/(l0+l1) -> bf16 ----------------
// grid (64 bh, 8 q-blocks); thread handles one q-row x 16 d.

__global__ __launch_bounds__(256) void attn_combine_kernel(
    const float* __restrict__ up, const float* __restrict__ lpart,
    const float* __restrict__ gate, const float* __restrict__ attw,
    const float* __restrict__ vcs, uint16_t* __restrict__ ctxh) {
  const int bh = blockIdx.x;
  const int q0 = blockIdx.y * 64;
  const int tid = threadIdx.x;
  const int row = tid >> 2;           // 0..63
  const int d0 = (tid & 3) * 16;      // 0,16,32,48
  const int qr = q0 + row;

  const float g = gate[bh];
  const float w = attw[0];
  const float c1 = w / ((float)NX + g);
  const float c2 = w * g / ((float)NX + g) + (1.f - w);
  const int b = bh >> 4, h = bh & 15;

  const size_t p0 = ((size_t)(0 * 64 + bh) * NQ + qr) * DH;
  const size_t p1 = ((size_t)(1 * 64 + bh) * NQ + qr) * DH;
  const float l = lpart[(size_t)(0 * 64 + bh) * NQ + qr] +
                  lpart[(size_t)(1 * 64 + bh) * NQ + qr];
  const float rl = 1.f / l;

  uint16_t* outp = ctxh + (((size_t)b * NQ + qr) * NH + h) * DH + d0;
#pragma unroll
  for (int jj = 0; jj < 4; ++jj) {
    float4 u0 = *(const float4*)&up[p0 + d0 + jj * 4];
    float4 u1 = *(const float4*)&up[p1 + d0 + jj * 4];
    float4 cv = *(const float4*)&vcs[bh * DH + d0 + jj * 4];
    ushort4 o;
    o.x = f2bf(c1 * cv.x + c2 * (u0.x + u1.x) * rl);
    o.y = f2bf(c1 * cv.y + c2 * (u0.y + u1.y) * rl);
    o.z = f2bf(c1 * cv.z + c2 * (u0.z + u1.z) * rl);
    o.w = f2bf(c1 * cv.w + c2 * (u0.w + u1.w) * rl);
    *(ushort4*)&outp[jj * 4] = o;
  }
}

// ---------------- launch ----------------

extern "C" void kernel_launch(void* const* d_in, const int* in_sizes, int n_in,
                              void* d_out, int out_size, void* d_ws,
                              size_t ws_size, hipStream_t stream) {
  const float* x = (const float*)d_in[0];
  const float* cls = (const float*)d_in[1];
  const float* w_kv = (const float*)d_in[2];
  const float* w_q = (const float*)d_in[3];
  const float* w_la = (const float*)d_in[4];
  const float* w_proj = (const float*)d_in[5];
  const float* b_proj = (const float*)d_in[6];
  const float* att_w = (const float*)d_in[7];
  float* out = (float*)d_out;

  char* ws = (char*)d_ws;
  size_t off = 0;
  auto alloc = [&](size_t bytes) {
    void* p = ws + off;
    off += (bytes + 255) & ~(size_t)255;
    return p;
  };
  uint16_t* xh = (uint16_t*)alloc(4ull * NX * CDIM * 2);
  uint16_t* ch = (uint16_t*)alloc(4ull * NQ * CDIM * 2);
  uint16_t* wkvT = (uint16_t*)alloc(2048ull * 1024 * 2);
  uint16_t* wqT = (uint16_t*)alloc(1024ull * 1024 * 2);
  uint16_t* wpT = (uint16_t*)alloc(1024ull * 1024 * 2);
  uint16_t* kbf = (uint16_t*)alloc(4ull * NH * NX * DH * 2);
  uint16_t* vT = (uint16_t*)alloc(4ull * NH * DH * NX * 2);
  uint16_t* qbf = (uint16_t*)alloc(4ull * NH * NQ * DH * 2);
  float* gv = (float*)alloc(4ull * NH * NX * 4);
  float* gate = (float*)alloc(1024);
  float* vcs = (float*)alloc(4ull * NH * DH * 4);
  uint16_t* ctxh = (uint16_t*)alloc(4ull * NQ * CDIM * 2);
  float* up = (float*)alloc(2ull * 64 * NQ * DH * 4);     // 16.8 MB
  float* lpart = (float*)alloc(2ull * 64 * NQ * 4);       // 256 KB

  cast2_bf16_kernel<<<2048, 256, 0, stream>>>(x, xh, 4 * NX * CDIM / 4,
                                              cls, ch, 4 * NQ * CDIM / 4);
  transT_all_kernel<<<dim3(32, 16, 3), 256, 0, stream>>>(w_kv, wkvT, w_q, wqT,
                                                         w_proj, wpT);

  aux_mm_kernel<<<256, 256, 0, stream>>>(ch, wqT, qbf, xh, w_la, gv);
  gemm_kv8<<<dim3(32, 8), 512, 0, stream>>>(xh, wkvT, kbf, vT);

  gate2_kernel<<<64, 256, 0, stream>>>(gv, gate);
  vcolsum_kernel<<<dim3(64, 4), 256, 0, stream>>>(vT, vcs);

  attn_part_kernel<<<dim3(64, 8, 2), 256, 0, stream>>>(qbf, kbf, vT, up, lpart);
  attn_combine_kernel<<<dim3(64, 8), 256, 0, stream>>>(up, lpart, gate, att_w,
                                                       vcs, ctxh);

  gemm_proj<<<dim3(16, 8), 256, 0, stream>>>(ctxh, wpT, out, b_proj);
}

// Round 13
// 142.459 us; speedup vs baseline: 1.0654x; 1.0654x over previous
//
#include <hip/hip_runtime.h>
#include <stdint.h>

#define NX 2048
#define NQ 512
#define CDIM 1024
#define NH 16
#define DH 64

typedef __attribute__((ext_vector_type(8))) __bf16 bf16x8;
typedef __attribute__((ext_vector_type(4))) float f32x4;

__device__ __forceinline__ uint16_t f2bf(float f) {
  uint32_t i = __float_as_uint(f);
  uint32_t r = i + 0x7fffu + ((i >> 16) & 1u);
  return (uint16_t)(r >> 16);
}

#define GLD16(g, l)                                                            \
  __builtin_amdgcn_global_load_lds(                                            \
      (const __attribute__((address_space(1))) uint32_t*)(g),                  \
      (__attribute__((address_space(3))) uint32_t*)(l), 16, 0, 0)

// ---------------- fused casts: x->xh and cls->ch in one launch ----------------

__global__ __launch_bounds__(256) void cast2_bf16_kernel(
    const float* __restrict__ s0, uint16_t* __restrict__ d0, int n40,
    const float* __restrict__ s1, uint16_t* __restrict__ d1, int n41) {
  int i = blockIdx.x * blockDim.x + threadIdx.x;
  int stride = gridDim.x * blockDim.x;
  int ntot = n40 + n41;
  for (; i < ntot; i += stride) {
    if (i < n40) {
      float4 v = ((const float4*)s0)[i];
      ushort4 o;
      o.x = f2bf(v.x); o.y = f2bf(v.y); o.z = f2bf(v.z); o.w = f2bf(v.w);
      ((ushort4*)d0)[i] = o;
    } else {
      float4 v = ((const float4*)s1)[i - n40];
      ushort4 o;
      o.x = f2bf(v.x); o.y = f2bf(v.y); o.z = f2bf(v.z); o.w = f2bf(v.w);
      ((ushort4*)d1)[i - n40] = o;
    }
  }
}

// ---------------- fused weight transposes: w_kv, w_q, w_proj in one launch ----------------

__global__ __launch_bounds__(256) void transT_all_kernel(
    const float* __restrict__ w_kv, uint16_t* __restrict__ wkvT,
    const float* __restrict__ w_q, uint16_t* __restrict__ wqT,
    const float* __restrict__ w_proj, uint16_t* __restrict__ wpT) {
  const int z = blockIdx.z;
  const float* src;
  uint16_t* dst;
  int N;
  if (z == 0) { src = w_kv; dst = wkvT; N = 2048; }
  else if (z == 1) { src = w_q; dst = wqT; N = 1024; }
  else { src = w_proj; dst = wpT; N = 1024; }
  const int n0 = blockIdx.x * 64;
  if (n0 >= N) return;
  const int k0 = blockIdx.y * 64;
  __shared__ uint16_t tile[64][65];
  const int tid = threadIdx.x;
#pragma unroll
  for (int it = 0; it < 16; ++it) {
    int idx = it * 256 + tid;
    int r = idx >> 6, c = idx & 63;
    tile[r][c] = f2bf(src[(size_t)(k0 + r) * N + n0 + c]);
  }
  __syncthreads();
#pragma unroll
  for (int it = 0; it < 16; ++it) {
    int idx = it * 256 + tid;
    int r = idx >> 6, c = idx & 63;
    dst[(size_t)(n0 + r) * 1024 + k0 + c] = tile[c][r];
  }
}

// ---------------- aux_mm: q-proj (blocks 0..127) + gate GEMV (blocks 128..255) ----------------

__global__ __launch_bounds__(256) void aux_mm_kernel(
    const uint16_t* __restrict__ ch, const uint16_t* __restrict__ wqT,
    uint16_t* __restrict__ qbf, const uint16_t* __restrict__ xh,
    const float* __restrict__ wla, float* __restrict__ gv) {
  __shared__ __align__(16) uint16_t smem[16 * 1024];  // 32 KB union
  const int tid = threadIdx.x;
  const int wv = tid >> 6;
  const int lane = tid & 63;
  const int lr = lane & 15;
  const int lh = lane >> 4;

  if (blockIdx.x < 128) {
    uint16_t* sA = smem;
    uint16_t* sB = smem + 128 * 32;
    const int wm = wv >> 1, wn = wv & 1;
    const int rowBase = (blockIdx.x & 15) * 128;
    const int colBase = (blockIdx.x >> 4) * 128;

    f32x4 zero4 = {0.f, 0.f, 0.f, 0.f};
    f32x4 acc[4][4];
#pragma unroll
    for (int m = 0; m < 4; ++m)
#pragma unroll
      for (int n = 0; n < 4; ++n) acc[m][n] = zero4;

    for (int k0 = 0; k0 < 1024; k0 += 32) {
#pragma unroll
      for (int it = 0; it < 2; ++it) {
        int s = it * 256 + tid;
        int row = s >> 2, cc = s & 3;
        int sc = cc ^ ((row >> 1) & 3);
        GLD16(ch + (size_t)(rowBase + row) * 1024 + k0 + sc * 8,
              sA + ((size_t)it * 256 + wv * 64) * 8);
        GLD16(wqT + (size_t)(colBase + row) * 1024 + k0 + sc * 8,
              sB + ((size_t)it * 256 + wv * 64) * 8);
      }
      __syncthreads();
      bf16x8 af[4], bfr[4];
#pragma unroll
      for (int m = 0; m < 4; ++m) {
        int r = wm * 64 + m * 16 + lr;
        af[m] = *(const bf16x8*)&sA[r * 32 + ((lh ^ ((r >> 1) & 3)) << 3)];
      }
#pragma unroll
      for (int n = 0; n < 4; ++n) {
        int r = wn * 64 + n * 16 + lr;
        bfr[n] = *(const bf16x8*)&sB[r * 32 + ((lh ^ ((r >> 1) & 3)) << 3)];
      }
#pragma unroll
      for (int m = 0; m < 4; ++m)
#pragma unroll
        for (int n = 0; n < 4; ++n)
          acc[m][n] = __builtin_amdgcn_mfma_f32_16x16x32_bf16(af[m], bfr[n],
                                                              acc[m][n], 0, 0, 0);
      __syncthreads();
    }

#pragma unroll
    for (int m = 0; m < 4; ++m) {
      int gr0 = rowBase + wm * 64 + m * 16 + lh * 4;
      int b = gr0 >> 9, nq0 = gr0 & 511;
#pragma unroll
      for (int n = 0; n < 4; ++n) {
        int gc = colBase + wn * 64 + n * 16 + lr;
        int hh = gc >> 6, d = gc & 63;
        size_t base = (((size_t)b * NH + hh) * NQ + nq0) * DH + d;
#pragma unroll
        for (int j = 0; j < 4; ++j)
          qbf[base + (size_t)j * DH] = f2bf(acc[m][n][j] * 0.125f);
      }
    }
  } else {
    uint16_t* sW = smem;
#pragma unroll
    for (int it = 0; it < 64; ++it) {
      int i = it * 256 + tid;
      int c = i >> 4, h = i & 15;
      sW[h * 1024 + (((c >> 3) ^ (h & 7)) << 3) + (c & 7)] = f2bf(wla[i]);
    }
    __syncthreads();

    const int rb = (blockIdx.x - 128) * 64 + wv * 16;
    f32x4 acc = {0.f, 0.f, 0.f, 0.f};
    for (int t = 0; t < 32; ++t) {
      bf16x8 af = *(const bf16x8*)&xh[(size_t)(rb + lr) * 1024 + t * 32 + lh * 8];
      bf16x8 bf = *(const bf16x8*)&sW[lr * 1024 + (((t * 4 + lh) ^ (lr & 7)) << 3)];
      acc = __builtin_amdgcn_mfma_f32_16x16x32_bf16(af, bf, acc, 0, 0, 0);
    }
    int nxg = rb + lh * 4;
    int b = nxg >> 11, nx = nxg & 2047;
    float4 st = {acc[0], acc[1], acc[2], acc[3]};
    *(float4*)&gv[((size_t)b * NH + lr) * NX + nx] = st;
  }
}

// ---------------- 8-phase 256x256 GEMM for x@w_kv (round-8 proven, 256 blocks = 1/CU) ----------------

__global__ __launch_bounds__(512, 2) void gemm_kv8(
    const uint16_t* __restrict__ A, const uint16_t* __restrict__ BT,
    uint16_t* __restrict__ outK, uint16_t* __restrict__ outV) {
  __shared__ __align__(16) uint16_t lds[65536];  // [buf][A|B][256][64]

  const int tid = threadIdx.x;
  const int wid = tid >> 6;
  const int lane = tid & 63;
  const int lr = lane & 15;
  const int lh = lane >> 4;
  const int wm = wid >> 2;
  const int wn = wid & 3;
  const int rowBase = blockIdx.x * 256;
  const int colBase = blockIdx.y * 256;

  f32x4 acc[8][4];
#pragma unroll
  for (int m = 0; m < 8; ++m)
#pragma unroll
    for (int n = 0; n < 4; ++n) acc[m][n] = (f32x4){0.f, 0.f, 0.f, 0.f};

  auto stageB = [&](int T, int h) {
    const uint16_t* srcp = BT + (size_t)(colBase + h * 128) * 1024 + T * 64;
    uint16_t* dst = lds + ((T & 1) * 32768 + 16384 + h * 8192);
#pragma unroll
    for (int it = 0; it < 2; ++it) {
      int s = it * 512 + tid;
      int row = s >> 3, cc = s & 7;
      int sc = cc ^ (row & 7);
      GLD16(srcp + (size_t)row * 1024 + sc * 8,
            dst + ((size_t)it * 512 + wid * 64) * 8);
    }
  };
  auto stageA012 = [&](int T) {
    const uint16_t* srcp = A + (size_t)rowBase * 1024 + T * 64;
    uint16_t* dstbase = lds + (T & 1) * 32768;
    int r64 = tid >> 3, cc = tid & 7;
#pragma unroll
    for (int st = 0; st < 3; ++st) {
      int rloc = (r64 < 32) ? (st * 32 + r64) : (96 + st * 32 + r64);
      int sc = cc ^ (rloc & 7);
      int wrow = (wid < 4) ? (st * 32 + wid * 8) : (128 + st * 32 + (wid - 4) * 8);
      GLD16(srcp + (size_t)rloc * 1024 + sc * 8, dstbase + (size_t)wrow * 64);
    }
  };
  auto stageA3 = [&](int T) {
    const uint16_t* srcp = A + (size_t)rowBase * 1024 + T * 64;
    uint16_t* dstbase = lds + (T & 1) * 32768;
    int r64 = tid >> 3, cc = tid & 7;
    int rloc = (r64 < 32) ? (96 + r64) : (192 + r64);
    int sc = cc ^ (rloc & 7);
    int wrow = (wid < 4) ? (96 + wid * 8) : (224 + (wid - 4) * 8);
    GLD16(srcp + (size_t)rloc * 1024 + sc * 8, dstbase + (size_t)wrow * 64);
  };

  auto rdA = [&](int p, int m, int kk) -> bf16x8 {
    int r = wm * 128 + m * 16 + lr;
    return *(const bf16x8*)&lds[p * 32768 + r * 64 +
                                (((kk * 4 + lh) ^ (r & 7)) << 3)];
  };
  auto rdB = [&](int p, int n, int kk) -> bf16x8 {
    int r = wn * 64 + n * 16 + lr;
    return *(const bf16x8*)&lds[p * 32768 + 16384 + r * 64 +
                                (((kk * 4 + lh) ^ (r & 7)) << 3)];
  };

  auto tile4 = [&](int t, bool last) {
    const int p = t & 1;
    bf16x8 b[4][2], a0[2], a1[2];
#pragma unroll
    for (int q = 0; q < 4; ++q) {
      if (q == 0) {
#pragma unroll
        for (int n = 0; n < 4; ++n)
#pragma unroll
          for (int kk = 0; kk < 2; ++kk) b[n][kk] = rdB(p, n, kk);
      }
#pragma unroll
      for (int kk = 0; kk < 2; ++kk) {
        a0[kk] = rdA(p, 2 * q, kk);
        a1[kk] = rdA(p, 2 * q + 1, kk);
      }
      if (q == 0) {
        stageA3(t + 1);
      } else if (q == 1) {
        if (!last) stageB(t + 2, 0);
      } else if (q == 2) {
        if (!last) stageB(t + 2, 1);
      } else {
        if (!last) stageA012(t + 2);
        if (last)
          asm volatile("s_waitcnt vmcnt(0)" ::: "memory");
        else
          asm volatile("s_waitcnt vmcnt(7)" ::: "memory");
      }
      __builtin_amdgcn_s_barrier();
      asm volatile("s_waitcnt lgkmcnt(0)" ::: "memory");
      __builtin_amdgcn_sched_barrier(0);
      __builtin_amdgcn_s_setprio(1);
#pragma unroll
      for (int n = 0; n < 4; ++n)
#pragma unroll
        for (int kk = 0; kk < 2; ++kk) {
          acc[2 * q][n] = __builtin_amdgcn_mfma_f32_16x16x32_bf16(
              a0[kk], b[n][kk], acc[2 * q][n], 0, 0, 0);
          acc[2 * q + 1][n] = __builtin_amdgcn_mfma_f32_16x16x32_bf16(
              a1[kk], b[n][kk], acc[2 * q + 1][n], 0, 0, 0);
        }
      __builtin_amdgcn_s_setprio(0);
      __builtin_amdgcn_s_barrier();
      asm volatile("" ::: "memory");
    }
  };

  auto tileEpi = [&](int t) {
    const int p = t & 1;
    bf16x8 b[4][2], a0[2], a1[2];
#pragma unroll
    for (int n = 0; n < 4; ++n)
#pragma unroll
      for (int kk = 0; kk < 2; ++kk) b[n][kk] = rdB(p, n, kk);
#pragma unroll
    for (int q = 0; q < 4; ++q) {
#pragma unroll
      for (int kk = 0; kk < 2; ++kk) {
        a0[kk] = rdA(p, 2 * q, kk);
        a1[kk] = rdA(p, 2 * q + 1, kk);
      }
#pragma unroll
      for (int n = 0; n < 4; ++n)
#pragma unroll
        for (int kk = 0; kk < 2; ++kk) {
          acc[2 * q][n] = __builtin_amdgcn_mfma_f32_16x16x32_bf16(
              a0[kk], b[n][kk], acc[2 * q][n], 0, 0, 0);
          acc[2 * q + 1][n] = __builtin_amdgcn_mfma_f32_16x16x32_bf16(
              a1[kk], b[n][kk], acc[2 * q + 1][n], 0, 0, 0);
        }
    }
  };

  stageB(0, 0); stageB(0, 1); stageA012(0); stageA3(0);
  stageB(1, 0); stageB(1, 1); stageA012(1);
  asm volatile("s_waitcnt vmcnt(7)" ::: "memory");
  __builtin_amdgcn_s_barrier();

  for (int t = 0; t < 14; ++t) tile4(t, false);
  tile4(14, true);
  tileEpi(15);

#pragma unroll
  for (int m = 0; m < 8; ++m) {
    int gr0 = rowBase + wm * 128 + m * 16 + lh * 4;
    int b_ = gr0 >> 11, nx0 = gr0 & 2047;
#pragma unroll
    for (int n = 0; n < 4; ++n) {
      int gc = colBase + wn * 64 + n * 16 + lr;
      if (gc < 1024) {
        int hh = gc >> 6, d = gc & 63;
        size_t base = (((size_t)b_ * NH + hh) * NX + nx0) * DH + d;
#pragma unroll
        for (int j = 0; j < 4; ++j)
          outK[base + (size_t)j * DH] = f2bf(acc[m][n][j]);
      } else {
        int c2 = gc - 1024;
        int hh = c2 >> 6, d = c2 & 63;
        ushort4 pv;
        pv.x = f2bf(acc[m][n][0]);
        pv.y = f2bf(acc[m][n][1]);
        pv.z = f2bf(acc[m][n][2]);
        pv.w = f2bf(acc[m][n][3]);
        *(ushort4*)&outV[(((size_t)b_ * NH + hh) * DH + d) * NX + nx0] = pv;
      }
    }
  }
}

// ---------------- 128x128 GEMM: ctx@w_proj + bias -> out fp32 ----------------

__global__ __launch_bounds__(256) void gemm_proj(
    const uint16_t* __restrict__ A, const uint16_t* __restrict__ BT,
    float* __restrict__ outF, const float* __restrict__ bias) {
  constexpr int K = 1024;
  __shared__ __align__(16) uint16_t sA[128 * 32];
  __shared__ __align__(16) uint16_t sB[128 * 32];

  const int tid = threadIdx.x;
  const int wv = tid >> 6;
  const int lane = tid & 63;
  const int lr = lane & 15;
  const int lh = lane >> 4;
  const int wm = wv >> 1, wn = wv & 1;
  const int rowBase = blockIdx.x * 128;
  const int colBase = blockIdx.y * 128;

  f32x4 zero4 = {0.f, 0.f, 0.f, 0.f};
  f32x4 acc[4][4];
#pragma unroll
  for (int m = 0; m < 4; ++m)
#pragma unroll
    for (int n = 0; n < 4; ++n) acc[m][n] = zero4;

  for (int k0 = 0; k0 < K; k0 += 32) {
#pragma unroll
    for (int it = 0; it < 2; ++it) {
      int s = it * 256 + tid;
      int row = s >> 2, cc = s & 3;
      int sc = cc ^ ((row >> 1) & 3);
      GLD16(A + (size_t)(rowBase + row) * K + k0 + sc * 8,
            sA + ((size_t)it * 256 + wv * 64) * 8);
      GLD16(BT + (size_t)(colBase + row) * K + k0 + sc * 8,
            sB + ((size_t)it * 256 + wv * 64) * 8);
    }
    __syncthreads();
    bf16x8 af[4], bfr[4];
#pragma unroll
    for (int m = 0; m < 4; ++m) {
      int r = wm * 64 + m * 16 + lr;
      af[m] = *(const bf16x8*)&sA[r * 32 + ((lh ^ ((r >> 1) & 3)) << 3)];
    }
#pragma unroll
    for (int n = 0; n < 4; ++n) {
      int r = wn * 64 + n * 16 + lr;
      bfr[n] = *(const bf16x8*)&sB[r * 32 + ((lh ^ ((r >> 1) & 3)) << 3)];
    }
#pragma unroll
    for (int m = 0; m < 4; ++m)
#pragma unroll
      for (int n = 0; n < 4; ++n)
        acc[m][n] = __builtin_amdgcn_mfma_f32_16x16x32_bf16(af[m], bfr[n],
                                                            acc[m][n], 0, 0, 0);
    __syncthreads();
  }

#pragma unroll
  for (int m = 0; m < 4; ++m) {
    int gr0 = rowBase + wm * 64 + m * 16 + lh * 4;
#pragma unroll
    for (int n = 0; n < 4; ++n) {
      int gc = colBase + wn * 64 + n * 16 + lr;
      float bi = bias[gc];
#pragma unroll
      for (int j = 0; j < 4; ++j)
        outF[(size_t)(gr0 + j) * 1024 + gc] = acc[m][n][j] + bi;
    }
  }
}

// ---------------- gate reduce ----------------

__global__ __launch_bounds__(256) void gate2_kernel(
    const float* __restrict__ gv, float* __restrict__ gate) {
  const int bh = blockIdx.x;
  const int tid = threadIdx.x;
  const float* p = gv + (size_t)bh * NX;
  float s = 0.f, mx = -1e30f;
  for (int i = tid; i < NX; i += 256) {
    float v = p[i];
    s += v;
    mx = fmaxf(mx, v);
  }
#pragma unroll
  for (int off = 1; off < 64; off <<= 1) {
    s += __shfl_xor(s, off, 64);
    mx = fmaxf(mx, __shfl_xor(mx, off, 64));
  }
  __shared__ float ss[4], sm[4];
  int wv = tid >> 6, lane = tid & 63;
  if (lane == 0) { ss[wv] = s; sm[wv] = mx; }
  __syncthreads();
  if (tid == 0) {
    float S = ss[0] + ss[1] + ss[2] + ss[3];
    float M = fmaxf(fmaxf(sm[0], sm[1]), fmaxf(sm[2], sm[3]));
    gate[bh] = 0.5f * (S / (float)NX) + 0.5f * M;
  }
}

// ---------------- column sum of V ----------------

__global__ __launch_bounds__(256) void vcolsum_kernel(
    const uint16_t* __restrict__ VT, float* __restrict__ vcs) {
  const int bh = blockIdx.x;
  const int wv = threadIdx.x >> 6, lane = threadIdx.x & 63;
#pragma unroll
  for (int dd = 0; dd < 4; ++dd) {
    int d = blockIdx.y * 16 + dd * 4 + wv;
    const uint16_t* row = VT + ((size_t)bh * DH + d) * NX;
    float s = 0.f;
#pragma unroll
    for (int i = 0; i < 4; ++i) {
      bf16x8 v = *(const bf16x8*)&row[(i * 64 + lane) * 8];
#pragma unroll
      for (int j = 0; j < 8; ++j) s += (float)v[j];
    }
#pragma unroll
    for (int off = 1; off < 64; off <<= 1) s += __shfl_xor(s, off, 64);
    if (lane == 0) vcs[bh * DH + d] = s;
  }
}

// ---------------- attention: single-pass flash, double-buffered K/V staging ----------------
// Round-13: T3/T4 applied to attention. Raw s_barrier + counted vmcnt(8):
// stage tile t+1 into buf^1 while computing tile t from buf. Ledger: 8
// loads/thread/tile; after issuing t+1's 8, vmcnt(8) -> t landed, t+1 in
// flight (never 0 in loop). Race-safety: stage(t+1) writes buf^1 whose last
// readers (PV of t-1) finished before the t-1-end barrier preceding issue.
// sPe single-buffered (write -> lgkmcnt(0) -> barrier -> read within tile).
// LDS 80 KB -> 2 blocks/CU (same as round-8); change is latency hiding.

__global__ __launch_bounds__(256) void attn_kernel(
    const uint16_t* __restrict__ Q, const uint16_t* __restrict__ K,
    const uint16_t* __restrict__ VT, const float* __restrict__ gate,
    const float* __restrict__ attw, const float* __restrict__ vcs,
    uint16_t* __restrict__ ctxh) {
  __shared__ __align__(16) uint16_t sK[2][128 * 64];
  __shared__ __align__(16) uint16_t sV[2][64 * 128];
  __shared__ __align__(16) __bf16 sPe[64 * 128];

  const int tid = threadIdx.x;
  const int wv = tid >> 6;
  const int lane = tid & 63;
  const int lr = lane & 15;
  const int lh = lane >> 4;
  const int bh = blockIdx.x;
  const int q0 = blockIdx.y * 64;
  const float g = gate[bh];
  const float w = attw[0];

  const uint16_t* Qb = Q + ((size_t)bh * NQ + q0) * DH;
  const uint16_t* Kb = K + (size_t)bh * NX * DH;
  const uint16_t* Vb = VT + (size_t)bh * DH * NX;

  auto stageKV = [&](int kt, int p) {  // 8 loads/thread
#pragma unroll
    for (int it = 0; it < 4; ++it) {
      int s = it * 256 + tid;
      int row = s >> 3, cc = s & 7;
      int sc = cc ^ (row & 7);
      GLD16(Kb + (size_t)(kt * 128 + row) * DH + sc * 8,
            sK[p] + ((size_t)it * 256 + wv * 64) * 8);
    }
#pragma unroll
    for (int it = 0; it < 4; ++it) {
      int s = it * 256 + tid;
      int row = s >> 4, cc = s & 15;
      int sc = cc ^ (row & 15);
      GLD16(Vb + (size_t)row * NX + kt * 128 + sc * 8,
            sV[p] + ((size_t)it * 256 + wv * 64) * 8);
    }
  };

  bf16x8 qa[2];
#pragma unroll
  for (int kk = 0; kk < 2; ++kk)
    qa[kk] = *(const bf16x8*)&Qb[(wv * 16 + lr) * DH + kk * 32 + lh * 8];

  float lp[4] = {0.f, 0.f, 0.f, 0.f};
  f32x4 zero4 = {0.f, 0.f, 0.f, 0.f};
  f32x4 accp[4];
#pragma unroll
  for (int d = 0; d < 4; ++d) accp[d] = zero4;

  stageKV(0, 0);  // prologue

  for (int kt = 0; kt < 16; ++kt) {
    const int p = kt & 1;
    if (kt < 15) {
      stageKV(kt + 1, p ^ 1);
      asm volatile("s_waitcnt vmcnt(8)" ::: "memory");
    } else {
      asm volatile("s_waitcnt vmcnt(0)" ::: "memory");
    }
    __builtin_amdgcn_s_barrier();  // tile kt's K/V visible to all waves
#pragma unroll
    for (int n = 0; n < 8; ++n) {
      f32x4 a4 = {0.f, 0.f, 0.f, 0.f};
      int r = n * 16 + lr;
#pragma unroll
      for (int kk = 0; kk < 2; ++kk) {
        bf16x8 kb =
            *(const bf16x8*)&sK[p][r * 64 + (((kk * 4 + lh) ^ (r & 7)) << 3)];
        a4 = __builtin_amdgcn_mfma_f32_16x16x32_bf16(qa[kk], kb, a4, 0, 0, 0);
      }
#pragma unroll
      for (int j = 0; j < 4; ++j) {
        float e = __expf(a4[j]);
        lp[j] += e;
        int qr = wv * 16 + lh * 4 + j;
        int key = n * 16 + lr;
        int idx = qr * 128 + ((((key >> 3) ^ (qr & 15))) << 3) + (key & 7);
        sPe[idx] = (__bf16)e;
      }
    }
    asm volatile("s_waitcnt lgkmcnt(0)" ::: "memory");
    __builtin_amdgcn_s_barrier();  // sPe complete
    const int prow = wv * 16 + lr;
#pragma unroll
    for (int kk = 0; kk < 4; ++kk) {
      int pidx = prow * 128 + (((kk * 4 + lh) ^ (prow & 15)) << 3);
      bf16x8 pe = *(const bf16x8*)&sPe[pidx];
#pragma unroll
      for (int df = 0; df < 4; ++df) {
        int vr = df * 16 + lr;
        bf16x8 vb =
            *(const bf16x8*)&sV[p][vr * 128 + (((kk * 4 + lh) ^ (vr & 15)) << 3)];
        accp[df] = __builtin_amdgcn_mfma_f32_16x16x32_bf16(pe, vb, accp[df], 0, 0, 0);
      }
    }
    asm volatile("s_waitcnt lgkmcnt(0)" ::: "memory");
    __builtin_amdgcn_s_barrier();  // buf reads done before next stage to buf
  }
#pragma unroll
  for (int off = 1; off < 16; off <<= 1)
#pragma unroll
    for (int j = 0; j < 4; ++j) lp[j] += __shfl_xor(lp[j], off, 64);

  const int b = bh >> 4, h = bh & 15;
  const float c1 = w / ((float)NX + g);
  const float c2 = w * g / ((float)NX + g) + (1.f - w);
  float rl[4];
#pragma unroll
  for (int j = 0; j < 4; ++j) rl[j] = 1.f / lp[j];
#pragma unroll
  for (int df = 0; df < 4; ++df) {
    int d = df * 16 + lr;
    float cv = vcs[bh * DH + d];
#pragma unroll
    for (int j = 0; j < 4; ++j) {
      int qr = q0 + wv * 16 + lh * 4 + j;
      float p = accp[df][j] * rl[j];
      ctxh[(((size_t)b * NQ + qr) * NH + h) * DH + d] = f2bf(c1 * cv + c2 * p);
    }
  }
}

// ---------------- launch ----------------

extern "C" void kernel_launch(void* const* d_in, const int* in_sizes, int n_in,
                              void* d_out, int out_size, void* d_ws,
                              size_t ws_size, hipStream_t stream) {
  const float* x = (const float*)d_in[0];
  const float* cls = (const float*)d_in[1];
  const float* w_kv = (const float*)d_in[2];
  const float* w_q = (const float*)d_in[3];
  const float* w_la = (const float*)d_in[4];
  const float* w_proj = (const float*)d_in[5];
  const float* b_proj = (const float*)d_in[6];
  const float* att_w = (const float*)d_in[7];
  float* out = (float*)d_out;

  char* ws = (char*)d_ws;
  size_t off = 0;
  auto alloc = [&](size_t bytes) {
    void* p = ws + off;
    off += (bytes + 255) & ~(size_t)255;
    return p;
  };
  uint16_t* xh = (uint16_t*)alloc(4ull * NX * CDIM * 2);
  uint16_t* ch = (uint16_t*)alloc(4ull * NQ * CDIM * 2);
  uint16_t* wkvT = (uint16_t*)alloc(2048ull * 1024 * 2);
  uint16_t* wqT = (uint16_t*)alloc(1024ull * 1024 * 2);
  uint16_t* wpT = (uint16_t*)alloc(1024ull * 1024 * 2);
  uint16_t* kbf = (uint16_t*)alloc(4ull * NH * NX * DH * 2);
  uint16_t* vT = (uint16_t*)alloc(4ull * NH * DH * NX * 2);
  uint16_t* qbf = (uint16_t*)alloc(4ull * NH * NQ * DH * 2);
  float* gv = (float*)alloc(4ull * NH * NX * 4);
  float* gate = (float*)alloc(1024);
  float* vcs = (float*)alloc(4ull * NH * DH * 4);
  uint16_t* ctxh = (uint16_t*)alloc(4ull * NQ * CDIM * 2);

  cast2_bf16_kernel<<<2048, 256, 0, stream>>>(x, xh, 4 * NX * CDIM / 4,
                                              cls, ch, 4 * NQ * CDIM / 4);
  transT_all_kernel<<<dim3(32, 16, 3), 256, 0, stream>>>(w_kv, wkvT, w_q, wqT,
                                                         w_proj, wpT);

  aux_mm_kernel<<<256, 256, 0, stream>>>(ch, wqT, qbf, xh, w_la, gv);
  gemm_kv8<<<dim3(32, 8), 512, 0, stream>>>(xh, wkvT, kbf, vT);

  gate2_kernel<<<64, 256, 0, stream>>>(gv, gate);
  vcolsum_kernel<<<dim3(64, 4), 256, 0, stream>>>(vT, vcs);

  attn_kernel<<<dim3(64, 8), 256, 0, stream>>>(qbf, kbf, vT, gate, att_w, vcs, ctxh);

  gemm_proj<<<dim3(16, 8), 256, 0, stream>>>(ctxh, wpT, out, b_proj);
}

// Round 14
// 138.755 us; speedup vs baseline: 1.0939x; 1.0267x over previous
//
#include <hip/hip_runtime.h>
#include <stdint.h>

#define NX 2048
#define NQ 512
#define CDIM 1024
#define NH 16
#define DH 64

typedef __attribute__((ext_vector_type(8))) __bf16 bf16x8;
typedef __attribute__((ext_vector_type(4))) float f32x4;

__device__ __forceinline__ uint16_t f2bf(float f) {
  uint32_t i = __float_as_uint(f);
  uint32_t r = i + 0x7fffu + ((i >> 16) & 1u);
  return (uint16_t)(r >> 16);
}

#define GLD16(g, l)                                                            \
  __builtin_amdgcn_global_load_lds(                                            \
      (const __attribute__((address_space(1))) uint32_t*)(g),                  \
      (__attribute__((address_space(3))) uint32_t*)(l), 16, 0, 0)

// ---------------- prep: casts (x,cls) + weight transposes, one launch ----------------
// blocks 0..2047: grid-stride cast of x->xh and cls->ch (float4 -> ushort4).
// blocks 2048..3583: 64x64 LDS-tiled transpose of w_kv/w_q/w_proj -> bf16 [N][1024].

__global__ __launch_bounds__(256) void prep_kernel(
    const float* __restrict__ x, uint16_t* __restrict__ xh,
    const float* __restrict__ cls, uint16_t* __restrict__ ch,
    const float* __restrict__ w_kv, uint16_t* __restrict__ wkvT,
    const float* __restrict__ w_q, uint16_t* __restrict__ wqT,
    const float* __restrict__ w_proj, uint16_t* __restrict__ wpT) {
  __shared__ uint16_t tile[64][65];
  const int tid = threadIdx.x;
  const int bid = blockIdx.x;
  if (bid < 2048) {
    const int n40 = 4 * NX * CDIM / 4, n41 = 4 * NQ * CDIM / 4;
    const int ntot = n40 + n41;
    const int stride = 2048 * 256;
    for (int i = bid * 256 + tid; i < ntot; i += stride) {
      if (i < n40) {
        float4 v = ((const float4*)x)[i];
        ushort4 o;
        o.x = f2bf(v.x); o.y = f2bf(v.y); o.z = f2bf(v.z); o.w = f2bf(v.w);
        ((ushort4*)xh)[i] = o;
      } else {
        float4 v = ((const float4*)cls)[i - n40];
        ushort4 o;
        o.x = f2bf(v.x); o.y = f2bf(v.y); o.z = f2bf(v.z); o.w = f2bf(v.w);
        ((ushort4*)ch)[i - n40] = o;
      }
    }
  } else {
    const int rem = bid - 2048;          // 0..1535
    const int z = rem >> 9;              // 0..2
    const int bx = rem & 31, by = (rem >> 5) & 15;
    const float* src;
    uint16_t* dst;
    int N;
    if (z == 0) { src = w_kv; dst = wkvT; N = 2048; }
    else if (z == 1) { src = w_q; dst = wqT; N = 1024; }
    else { src = w_proj; dst = wpT; N = 1024; }
    const int n0 = bx * 64;
    if (n0 >= N) return;
    const int k0 = by * 64;
#pragma unroll
    for (int it = 0; it < 16; ++it) {
      int idx = it * 256 + tid;
      int r = idx >> 6, c = idx & 63;
      tile[r][c] = f2bf(src[(size_t)(k0 + r) * N + n0 + c]);
    }
    __syncthreads();
#pragma unroll
    for (int it = 0; it < 16; ++it) {
      int idx = it * 256 + tid;
      int r = idx >> 6, c = idx & 63;
      dst[(size_t)(n0 + r) * 1024 + k0 + c] = tile[c][r];
    }
  }
}

// ---------------- aux_mm: q-proj (blocks 0..127) + gate GEMV (blocks 128..255) ----------------

__global__ __launch_bounds__(256) void aux_mm_kernel(
    const uint16_t* __restrict__ ch, const uint16_t* __restrict__ wqT,
    uint16_t* __restrict__ qbf, const uint16_t* __restrict__ xh,
    const float* __restrict__ wla, float* __restrict__ gv) {
  __shared__ __align__(16) uint16_t smem[16 * 1024];  // 32 KB union
  const int tid = threadIdx.x;
  const int wv = tid >> 6;
  const int lane = tid & 63;
  const int lr = lane & 15;
  const int lh = lane >> 4;

  if (blockIdx.x < 128) {
    uint16_t* sA = smem;
    uint16_t* sB = smem + 128 * 32;
    const int wm = wv >> 1, wn = wv & 1;
    const int rowBase = (blockIdx.x & 15) * 128;
    const int colBase = (blockIdx.x >> 4) * 128;

    f32x4 zero4 = {0.f, 0.f, 0.f, 0.f};
    f32x4 acc[4][4];
#pragma unroll
    for (int m = 0; m < 4; ++m)
#pragma unroll
      for (int n = 0; n < 4; ++n) acc[m][n] = zero4;

    for (int k0 = 0; k0 < 1024; k0 += 32) {
#pragma unroll
      for (int it = 0; it < 2; ++it) {
        int s = it * 256 + tid;
        int row = s >> 2, cc = s & 3;
        int sc = cc ^ ((row >> 1) & 3);
        GLD16(ch + (size_t)(rowBase + row) * 1024 + k0 + sc * 8,
              sA + ((size_t)it * 256 + wv * 64) * 8);
        GLD16(wqT + (size_t)(colBase + row) * 1024 + k0 + sc * 8,
              sB + ((size_t)it * 256 + wv * 64) * 8);
      }
      __syncthreads();
      bf16x8 af[4], bfr[4];
#pragma unroll
      for (int m = 0; m < 4; ++m) {
        int r = wm * 64 + m * 16 + lr;
        af[m] = *(const bf16x8*)&sA[r * 32 + ((lh ^ ((r >> 1) & 3)) << 3)];
      }
#pragma unroll
      for (int n = 0; n < 4; ++n) {
        int r = wn * 64 + n * 16 + lr;
        bfr[n] = *(const bf16x8*)&sB[r * 32 + ((lh ^ ((r >> 1) & 3)) << 3)];
      }
#pragma unroll
      for (int m = 0; m < 4; ++m)
#pragma unroll
        for (int n = 0; n < 4; ++n)
          acc[m][n] = __builtin_amdgcn_mfma_f32_16x16x32_bf16(af[m], bfr[n],
                                                              acc[m][n], 0, 0, 0);
      __syncthreads();
    }

#pragma unroll
    for (int m = 0; m < 4; ++m) {
      int gr0 = rowBase + wm * 64 + m * 16 + lh * 4;
      int b = gr0 >> 9, nq0 = gr0 & 511;
#pragma unroll
      for (int n = 0; n < 4; ++n) {
        int gc = colBase + wn * 64 + n * 16 + lr;
        int hh = gc >> 6, d = gc & 63;
        size_t base = (((size_t)b * NH + hh) * NQ + nq0) * DH + d;
#pragma unroll
        for (int j = 0; j < 4; ++j)
          qbf[base + (size_t)j * DH] = f2bf(acc[m][n][j] * 0.125f);
      }
    }
  } else {
    uint16_t* sW = smem;
#pragma unroll
    for (int it = 0; it < 64; ++it) {
      int i = it * 256 + tid;
      int c = i >> 4, h = i & 15;
      sW[h * 1024 + (((c >> 3) ^ (h & 7)) << 3) + (c & 7)] = f2bf(wla[i]);
    }
    __syncthreads();

    const int rb = (blockIdx.x - 128) * 64 + wv * 16;
    f32x4 acc = {0.f, 0.f, 0.f, 0.f};
    for (int t = 0; t < 32; ++t) {
      bf16x8 af = *(const bf16x8*)&xh[(size_t)(rb + lr) * 1024 + t * 32 + lh * 8];
      bf16x8 bf = *(const bf16x8*)&sW[lr * 1024 + (((t * 4 + lh) ^ (lr & 7)) << 3)];
      acc = __builtin_amdgcn_mfma_f32_16x16x32_bf16(af, bf, acc, 0, 0, 0);
    }
    int nxg = rb + lh * 4;
    int b = nxg >> 11, nx = nxg & 2047;
    float4 st = {acc[0], acc[1], acc[2], acc[3]};
    *(float4*)&gv[((size_t)b * NH + lr) * NX + nx] = st;
  }
}

// ---------------- 8-phase 256x256 GEMM for x@w_kv (round-8 proven, 256 blocks = 1/CU) ----------------

__global__ __launch_bounds__(512, 2) void gemm_kv8(
    const uint16_t* __restrict__ A, const uint16_t* __restrict__ BT,
    uint16_t* __restrict__ outK, uint16_t* __restrict__ outV) {
  __shared__ __align__(16) uint16_t lds[65536];  // [buf][A|B][256][64]

  const int tid = threadIdx.x;
  const int wid = tid >> 6;
  const int lane = tid & 63;
  const int lr = lane & 15;
  const int lh = lane >> 4;
  const int wm = wid >> 2;
  const int wn = wid & 3;
  const int rowBase = blockIdx.x * 256;
  const int colBase = blockIdx.y * 256;

  f32x4 acc[8][4];
#pragma unroll
  for (int m = 0; m < 8; ++m)
#pragma unroll
    for (int n = 0; n < 4; ++n) acc[m][n] = (f32x4){0.f, 0.f, 0.f, 0.f};

  auto stageB = [&](int T, int h) {
    const uint16_t* srcp = BT + (size_t)(colBase + h * 128) * 1024 + T * 64;
    uint16_t* dst = lds + ((T & 1) * 32768 + 16384 + h * 8192);
#pragma unroll
    for (int it = 0; it < 2; ++it) {
      int s = it * 512 + tid;
      int row = s >> 3, cc = s & 7;
      int sc = cc ^ (row & 7);
      GLD16(srcp + (size_t)row * 1024 + sc * 8,
            dst + ((size_t)it * 512 + wid * 64) * 8);
    }
  };
  auto stageA012 = [&](int T) {
    const uint16_t* srcp = A + (size_t)rowBase * 1024 + T * 64;
    uint16_t* dstbase = lds + (T & 1) * 32768;
    int r64 = tid >> 3, cc = tid & 7;
#pragma unroll
    for (int st = 0; st < 3; ++st) {
      int rloc = (r64 < 32) ? (st * 32 + r64) : (96 + st * 32 + r64);
      int sc = cc ^ (rloc & 7);
      int wrow = (wid < 4) ? (st * 32 + wid * 8) : (128 + st * 32 + (wid - 4) * 8);
      GLD16(srcp + (size_t)rloc * 1024 + sc * 8, dstbase + (size_t)wrow * 64);
    }
  };
  auto stageA3 = [&](int T) {
    const uint16_t* srcp = A + (size_t)rowBase * 1024 + T * 64;
    uint16_t* dstbase = lds + (T & 1) * 32768;
    int r64 = tid >> 3, cc = tid & 7;
    int rloc = (r64 < 32) ? (96 + r64) : (192 + r64);
    int sc = cc ^ (rloc & 7);
    int wrow = (wid < 4) ? (96 + wid * 8) : (224 + (wid - 4) * 8);
    GLD16(srcp + (size_t)rloc * 1024 + sc * 8, dstbase + (size_t)wrow * 64);
  };

  auto rdA = [&](int p, int m, int kk) -> bf16x8 {
    int r = wm * 128 + m * 16 + lr;
    return *(const bf16x8*)&lds[p * 32768 + r * 64 +
                                (((kk * 4 + lh) ^ (r & 7)) << 3)];
  };
  auto rdB = [&](int p, int n, int kk) -> bf16x8 {
    int r = wn * 64 + n * 16 + lr;
    return *(const bf16x8*)&lds[p * 32768 + 16384 + r * 64 +
                                (((kk * 4 + lh) ^ (r & 7)) << 3)];
  };

  auto tile4 = [&](int t, bool last) {
    const int p = t & 1;
    bf16x8 b[4][2], a0[2], a1[2];
#pragma unroll
    for (int q = 0; q < 4; ++q) {
      if (q == 0) {
#pragma unroll
        for (int n = 0; n < 4; ++n)
#pragma unroll
          for (int kk = 0; kk < 2; ++kk) b[n][kk] = rdB(p, n, kk);
      }
#pragma unroll
      for (int kk = 0; kk < 2; ++kk) {
        a0[kk] = rdA(p, 2 * q, kk);
        a1[kk] = rdA(p, 2 * q + 1, kk);
      }
      if (q == 0) {
        stageA3(t + 1);
      } else if (q == 1) {
        if (!last) stageB(t + 2, 0);
      } else if (q == 2) {
        if (!last) stageB(t + 2, 1);
      } else {
        if (!last) stageA012(t + 2);
        if (last)
          asm volatile("s_waitcnt vmcnt(0)" ::: "memory");
        else
          asm volatile("s_waitcnt vmcnt(7)" ::: "memory");
      }
      __builtin_amdgcn_s_barrier();
      asm volatile("s_waitcnt lgkmcnt(0)" ::: "memory");
      __builtin_amdgcn_sched_barrier(0);
      __builtin_amdgcn_s_setprio(1);
#pragma unroll
      for (int n = 0; n < 4; ++n)
#pragma unroll
        for (int kk = 0; kk < 2; ++kk) {
          acc[2 * q][n] = __builtin_amdgcn_mfma_f32_16x16x32_bf16(
              a0[kk], b[n][kk], acc[2 * q][n], 0, 0, 0);
          acc[2 * q + 1][n] = __builtin_amdgcn_mfma_f32_16x16x32_bf16(
              a1[kk], b[n][kk], acc[2 * q + 1][n], 0, 0, 0);
        }
      __builtin_amdgcn_s_setprio(0);
      __builtin_amdgcn_s_barrier();
      asm volatile("" ::: "memory");
    }
  };

  auto tileEpi = [&](int t) {
    const int p = t & 1;
    bf16x8 b[4][2], a0[2], a1[2];
#pragma unroll
    for (int n = 0; n < 4; ++n)
#pragma unroll
      for (int kk = 0; kk < 2; ++kk) b[n][kk] = rdB(p, n, kk);
#pragma unroll
    for (int q = 0; q < 4; ++q) {
#pragma unroll
      for (int kk = 0; kk < 2; ++kk) {
        a0[kk] = rdA(p, 2 * q, kk);
        a1[kk] = rdA(p, 2 * q + 1, kk);
      }
#pragma unroll
      for (int n = 0; n < 4; ++n)
#pragma unroll
        for (int kk = 0; kk < 2; ++kk) {
          acc[2 * q][n] = __builtin_amdgcn_mfma_f32_16x16x32_bf16(
              a0[kk], b[n][kk], acc[2 * q][n], 0, 0, 0);
          acc[2 * q + 1][n] = __builtin_amdgcn_mfma_f32_16x16x32_bf16(
              a1[kk], b[n][kk], acc[2 * q + 1][n], 0, 0, 0);
        }
    }
  };

  stageB(0, 0); stageB(0, 1); stageA012(0); stageA3(0);
  stageB(1, 0); stageB(1, 1); stageA012(1);
  asm volatile("s_waitcnt vmcnt(7)" ::: "memory");
  __builtin_amdgcn_s_barrier();

  for (int t = 0; t < 14; ++t) tile4(t, false);
  tile4(14, true);
  tileEpi(15);

#pragma unroll
  for (int m = 0; m < 8; ++m) {
    int gr0 = rowBase + wm * 128 + m * 16 + lh * 4;
    int b_ = gr0 >> 11, nx0 = gr0 & 2047;
#pragma unroll
    for (int n = 0; n < 4; ++n) {
      int gc = colBase + wn * 64 + n * 16 + lr;
      if (gc < 1024) {
        int hh = gc >> 6, d = gc & 63;
        size_t base = (((size_t)b_ * NH + hh) * NX + nx0) * DH + d;
#pragma unroll
        for (int j = 0; j < 4; ++j)
          outK[base + (size_t)j * DH] = f2bf(acc[m][n][j]);
      } else {
        int c2 = gc - 1024;
        int hh = c2 >> 6, d = c2 & 63;
        ushort4 pv;
        pv.x = f2bf(acc[m][n][0]);
        pv.y = f2bf(acc[m][n][1]);
        pv.z = f2bf(acc[m][n][2]);
        pv.w = f2bf(acc[m][n][3]);
        *(ushort4*)&outV[(((size_t)b_ * NH + hh) * DH + d) * NX + nx0] = pv;
      }
    }
  }
}

// ---------------- 128x128 GEMM: ctx@w_proj + bias -> out fp32 ----------------

__global__ __launch_bounds__(256) void gemm_proj(
    const uint16_t* __restrict__ A, const uint16_t* __restrict__ BT,
    float* __restrict__ outF, const float* __restrict__ bias) {
  constexpr int K = 1024;
  __shared__ __align__(16) uint16_t sA[128 * 32];
  __shared__ __align__(16) uint16_t sB[128 * 32];

  const int tid = threadIdx.x;
  const int wv = tid >> 6;
  const int lane = tid & 63;
  const int lr = lane & 15;
  const int lh = lane >> 4;
  const int wm = wv >> 1, wn = wv & 1;
  const int rowBase = blockIdx.x * 128;
  const int colBase = blockIdx.y * 128;

  f32x4 zero4 = {0.f, 0.f, 0.f, 0.f};
  f32x4 acc[4][4];
#pragma unroll
  for (int m = 0; m < 4; ++m)
#pragma unroll
    for (int n = 0; n < 4; ++n) acc[m][n] = zero4;

  for (int k0 = 0; k0 < K; k0 += 32) {
#pragma unroll
    for (int it = 0; it < 2; ++it) {
      int s = it * 256 + tid;
      int row = s >> 2, cc = s & 3;
      int sc = cc ^ ((row >> 1) & 3);
      GLD16(A + (size_t)(rowBase + row) * K + k0 + sc * 8,
            sA + ((size_t)it * 256 + wv * 64) * 8);
      GLD16(BT + (size_t)(colBase + row) * K + k0 + sc * 8,
            sB + ((size_t)it * 256 + wv * 64) * 8);
    }
    __syncthreads();
    bf16x8 af[4], bfr[4];
#pragma unroll
    for (int m = 0; m < 4; ++m) {
      int r = wm * 64 + m * 16 + lr;
      af[m] = *(const bf16x8*)&sA[r * 32 + ((lh ^ ((r >> 1) & 3)) << 3)];
    }
#pragma unroll
    for (int n = 0; n < 4; ++n) {
      int r = wn * 64 + n * 16 + lr;
      bfr[n] = *(const bf16x8*)&sB[r * 32 + ((lh ^ ((r >> 1) & 3)) << 3)];
    }
#pragma unroll
    for (int m = 0; m < 4; ++m)
#pragma unroll
      for (int n = 0; n < 4; ++n)
        acc[m][n] = __builtin_amdgcn_mfma_f32_16x16x32_bf16(af[m], bfr[n],
                                                            acc[m][n], 0, 0, 0);
    __syncthreads();
  }

#pragma unroll
  for (int m = 0; m < 4; ++m) {
    int gr0 = rowBase + wm * 64 + m * 16 + lh * 4;
#pragma unroll
    for (int n = 0; n < 4; ++n) {
      int gc = colBase + wn * 64 + n * 16 + lr;
      float bi = bias[gc];
#pragma unroll
      for (int j = 0; j < 4; ++j)
        outF[(size_t)(gr0 + j) * 1024 + gc] = acc[m][n][j] + bi;
    }
  }
}

// ---------------- gatev: gate reduce (blocks 0..63) + vcolsum (blocks 64..319) ----------------

__global__ __launch_bounds__(256) void gatev_kernel(
    const float* __restrict__ gv, float* __restrict__ gate,
    const uint16_t* __restrict__ VT, float* __restrict__ vcs) {
  const int tid = threadIdx.x;
  const int wv = tid >> 6, lane = tid & 63;
  if (blockIdx.x < 64) {
    const int bh = blockIdx.x;
    const float* p = gv + (size_t)bh * NX;
    float s = 0.f, mx = -1e30f;
    for (int i = tid; i < NX; i += 256) {
      float v = p[i];
      s += v;
      mx = fmaxf(mx, v);
    }
#pragma unroll
    for (int off = 1; off < 64; off <<= 1) {
      s += __shfl_xor(s, off, 64);
      mx = fmaxf(mx, __shfl_xor(mx, off, 64));
    }
    __shared__ float ss[4], sm[4];
    if (lane == 0) { ss[wv] = s; sm[wv] = mx; }
    __syncthreads();
    if (tid == 0) {
      float S = ss[0] + ss[1] + ss[2] + ss[3];
      float M = fmaxf(fmaxf(sm[0], sm[1]), fmaxf(sm[2], sm[3]));
      gate[bh] = 0.5f * (S / (float)NX) + 0.5f * M;
    }
  } else {
    const int idx = blockIdx.x - 64;  // 0..255
    const int bh = idx & 63, quarter = idx >> 6;
#pragma unroll
    for (int dd = 0; dd < 4; ++dd) {
      int d = quarter * 16 + dd * 4 + wv;
      const uint16_t* row = VT + ((size_t)bh * DH + d) * NX;
      float s = 0.f;
#pragma unroll
      for (int i = 0; i < 4; ++i) {
        bf16x8 v = *(const bf16x8*)&row[(i * 64 + lane) * 8];
#pragma unroll
        for (int j = 0; j < 8; ++j) s += (float)v[j];
      }
#pragma unroll
      for (int off = 1; off < 64; off <<= 1) s += __shfl_xor(s, off, 64);
      if (lane == 0) vcs[bh * DH + d] = s;
    }
  }
}

// ---------------- attention: single-pass flash, dbuf K/V, 2 barriers/tile ----------------
// Round-14: sPe is WAVE-PRIVATE (write rows [wv*16,wv*16+16), read prow=wv*16+lr
// in the same range) -> the mid-tile block barrier is unnecessary; a wave-local
// lgkmcnt(0)+sched_barrier orders write->read (rule #18). Tile structure:
// {stage(t+1,p^1); vmcnt(8); s_barrier; QK+exp+sPe; lgkm(0) wave-local; PV;
//  s_barrier}. Counted vmcnt ledger identical to round-13 (proven).

__global__ __launch_bounds__(256) void attn_kernel(
    const uint16_t* __restrict__ Q, const uint16_t* __restrict__ K,
    const uint16_t* __restrict__ VT, const float* __restrict__ gate,
    const float* __restrict__ attw, const float* __restrict__ vcs,
    uint16_t* __restrict__ ctxh) {
  __shared__ __align__(16) uint16_t sK[2][128 * 64];
  __shared__ __align__(16) uint16_t sV[2][64 * 128];
  __shared__ __align__(16) __bf16 sPe[64 * 128];

  const int tid = threadIdx.x;
  const int wv = tid >> 6;
  const int lane = tid & 63;
  const int lr = lane & 15;
  const int lh = lane >> 4;
  const int bh = blockIdx.x;
  const int q0 = blockIdx.y * 64;
  const float g = gate[bh];
  const float w = attw[0];

  const uint16_t* Qb = Q + ((size_t)bh * NQ + q0) * DH;
  const uint16_t* Kb = K + (size_t)bh * NX * DH;
  const uint16_t* Vb = VT + (size_t)bh * DH * NX;

  auto stageKV = [&](int kt, int p) {  // 8 loads/thread
#pragma unroll
    for (int it = 0; it < 4; ++it) {
      int s = it * 256 + tid;
      int row = s >> 3, cc = s & 7;
      int sc = cc ^ (row & 7);
      GLD16(Kb + (size_t)(kt * 128 + row) * DH + sc * 8,
            sK[p] + ((size_t)it * 256 + wv * 64) * 8);
    }
#pragma unroll
    for (int it = 0; it < 4; ++it) {
      int s = it * 256 + tid;
      int row = s >> 4, cc = s & 15;
      int sc = cc ^ (row & 15);
      GLD16(Vb + (size_t)row * NX + kt * 128 + sc * 8,
            sV[p] + ((size_t)it * 256 + wv * 64) * 8);
    }
  };

  bf16x8 qa[2];
#pragma unroll
  for (int kk = 0; kk < 2; ++kk)
    qa[kk] = *(const bf16x8*)&Qb[(wv * 16 + lr) * DH + kk * 32 + lh * 8];

  float lp[4] = {0.f, 0.f, 0.f, 0.f};
  f32x4 zero4 = {0.f, 0.f, 0.f, 0.f};
  f32x4 accp[4];
#pragma unroll
  for (int d = 0; d < 4; ++d) accp[d] = zero4;

  stageKV(0, 0);  // prologue

  for (int kt = 0; kt < 16; ++kt) {
    const int p = kt & 1;
    if (kt < 15) {
      stageKV(kt + 1, p ^ 1);
      asm volatile("s_waitcnt vmcnt(8)" ::: "memory");
    } else {
      asm volatile("s_waitcnt vmcnt(0)" ::: "memory");
    }
    __builtin_amdgcn_s_barrier();  // tile kt's K/V visible to all waves
#pragma unroll
    for (int n = 0; n < 8; ++n) {
      f32x4 a4 = {0.f, 0.f, 0.f, 0.f};
      int r = n * 16 + lr;
#pragma unroll
      for (int kk = 0; kk < 2; ++kk) {
        bf16x8 kb =
            *(const bf16x8*)&sK[p][r * 64 + (((kk * 4 + lh) ^ (r & 7)) << 3)];
        a4 = __builtin_amdgcn_mfma_f32_16x16x32_bf16(qa[kk], kb, a4, 0, 0, 0);
      }
#pragma unroll
      for (int j = 0; j < 4; ++j) {
        float e = __expf(a4[j]);
        lp[j] += e;
        int qr = wv * 16 + lh * 4 + j;
        int key = n * 16 + lr;
        int idx = qr * 128 + ((((key >> 3) ^ (qr & 15))) << 3) + (key & 7);
        sPe[idx] = (__bf16)e;
      }
    }
    // sPe is wave-private: wave-local ordering only (no block barrier).
    asm volatile("s_waitcnt lgkmcnt(0)" ::: "memory");
    __builtin_amdgcn_sched_barrier(0);
    const int prow = wv * 16 + lr;
#pragma unroll
    for (int kk = 0; kk < 4; ++kk) {
      int pidx = prow * 128 + (((kk * 4 + lh) ^ (prow & 15)) << 3);
      bf16x8 pe = *(const bf16x8*)&sPe[pidx];
#pragma unroll
      for (int df = 0; df < 4; ++df) {
        int vr = df * 16 + lr;
        bf16x8 vb =
            *(const bf16x8*)&sV[p][vr * 128 + (((kk * 4 + lh) ^ (vr & 15)) << 3)];
        accp[df] = __builtin_amdgcn_mfma_f32_16x16x32_bf16(pe, vb, accp[df], 0, 0, 0);
      }
    }
    asm volatile("s_waitcnt lgkmcnt(0)" ::: "memory");
    __builtin_amdgcn_s_barrier();  // all waves done reading buf p before restage
  }
#pragma unroll
  for (int off = 1; off < 16; off <<= 1)
#pragma unroll
    for (int j = 0; j < 4; ++j) lp[j] += __shfl_xor(lp[j], off, 64);

  const int b = bh >> 4, h = bh & 15;
  const float c1 = w / ((float)NX + g);
  const float c2 = w * g / ((float)NX + g) + (1.f - w);
  float rl[4];
#pragma unroll
  for (int j = 0; j < 4; ++j) rl[j] = 1.f / lp[j];
#pragma unroll
  for (int df = 0; df < 4; ++df) {
    int d = df * 16 + lr;
    float cv = vcs[bh * DH + d];
#pragma unroll
    for (int j = 0; j < 4; ++j) {
      int qr = q0 + wv * 16 + lh * 4 + j;
      float p = accp[df][j] * rl[j];
      ctxh[(((size_t)b * NQ + qr) * NH + h) * DH + d] = f2bf(c1 * cv + c2 * p);
    }
  }
}

// ---------------- launch ----------------

extern "C" void kernel_launch(void* const* d_in, const int* in_sizes, int n_in,
                              void* d_out, int out_size, void* d_ws,
                              size_t ws_size, hipStream_t stream) {
  const float* x = (const float*)d_in[0];
  const float* cls = (const float*)d_in[1];
  const float* w_kv = (const float*)d_in[2];
  const float* w_q = (const float*)d_in[3];
  const float* w_la = (const float*)d_in[4];
  const float* w_proj = (const float*)d_in[5];
  const float* b_proj = (const float*)d_in[6];
  const float* att_w = (const float*)d_in[7];
  float* out = (float*)d_out;

  char* ws = (char*)d_ws;
  size_t off = 0;
  auto alloc = [&](size_t bytes) {
    void* p = ws + off;
    off += (bytes + 255) & ~(size_t)255;
    return p;
  };
  uint16_t* xh = (uint16_t*)alloc(4ull * NX * CDIM * 2);
  uint16_t* ch = (uint16_t*)alloc(4ull * NQ * CDIM * 2);
  uint16_t* wkvT = (uint16_t*)alloc(2048ull * 1024 * 2);
  uint16_t* wqT = (uint16_t*)alloc(1024ull * 1024 * 2);
  uint16_t* wpT = (uint16_t*)alloc(1024ull * 1024 * 2);
  uint16_t* kbf = (uint16_t*)alloc(4ull * NH * NX * DH * 2);
  uint16_t* vT = (uint16_t*)alloc(4ull * NH * DH * NX * 2);
  uint16_t* qbf = (uint16_t*)alloc(4ull * NH * NQ * DH * 2);
  float* gv = (float*)alloc(4ull * NH * NX * 4);
  float* gate = (float*)alloc(1024);
  float* vcs = (float*)alloc(4ull * NH * DH * 4);
  uint16_t* ctxh = (uint16_t*)alloc(4ull * NQ * CDIM * 2);

  prep_kernel<<<3584, 256, 0, stream>>>(x, xh, cls, ch, w_kv, wkvT, w_q, wqT,
                                        w_proj, wpT);

  aux_mm_kernel<<<256, 256, 0, stream>>>(ch, wqT, qbf, xh, w_la, gv);
  gemm_kv8<<<dim3(32, 8), 512, 0, stream>>>(xh, wkvT, kbf, vT);

  gatev_kernel<<<320, 256, 0, stream>>>(gv, gate, vT, vcs);

  attn_kernel<<<dim3(64, 8), 256, 0, stream>>>(qbf, kbf, vT, gate, att_w, vcs, ctxh);

  gemm_proj<<<dim3(16, 8), 256, 0, stream>>>(ctxh, wpT, out, b_proj);
}

// Round 15
// 134.177 us; speedup vs baseline: 1.1312x; 1.0341x over previous
//
#include <hip/hip_runtime.h>
#include <stdint.h>

#define NX 2048
#define NQ 512
#define CDIM 1024
#define NH 16
#define DH 64

typedef __attribute__((ext_vector_type(8))) __bf16 bf16x8;
typedef __attribute__((ext_vector_type(4))) float f32x4;

__device__ __forceinline__ uint16_t f2bf(float f) {
  uint32_t i = __float_as_uint(f);
  uint32_t r = i + 0x7fffu + ((i >> 16) & 1u);
  return (uint16_t)(r >> 16);
}

#define GLD16(g, l)                                                            \
  __builtin_amdgcn_global_load_lds(                                            \
      (const __attribute__((address_space(1))) uint32_t*)(g),                  \
      (__attribute__((address_space(3))) uint32_t*)(l), 16, 0, 0)

// ---------------- prep: casts (x,cls) + weight transposes, one launch ----------------

__global__ __launch_bounds__(256) void prep_kernel(
    const float* __restrict__ x, uint16_t* __restrict__ xh,
    const float* __restrict__ cls, uint16_t* __restrict__ ch,
    const float* __restrict__ w_kv, uint16_t* __restrict__ wkvT,
    const float* __restrict__ w_q, uint16_t* __restrict__ wqT,
    const float* __restrict__ w_proj, uint16_t* __restrict__ wpT) {
  __shared__ uint16_t tile[64][65];
  const int tid = threadIdx.x;
  const int bid = blockIdx.x;
  if (bid < 2048) {
    const int n40 = 4 * NX * CDIM / 4, n41 = 4 * NQ * CDIM / 4;
    const int ntot = n40 + n41;
    const int stride = 2048 * 256;
    for (int i = bid * 256 + tid; i < ntot; i += stride) {
      if (i < n40) {
        float4 v = ((const float4*)x)[i];
        ushort4 o;
        o.x = f2bf(v.x); o.y = f2bf(v.y); o.z = f2bf(v.z); o.w = f2bf(v.w);
        ((ushort4*)xh)[i] = o;
      } else {
        float4 v = ((const float4*)cls)[i - n40];
        ushort4 o;
        o.x = f2bf(v.x); o.y = f2bf(v.y); o.z = f2bf(v.z); o.w = f2bf(v.w);
        ((ushort4*)ch)[i - n40] = o;
      }
    }
  } else {
    const int rem = bid - 2048;          // 0..1535
    const int z = rem >> 9;              // 0..2
    const int bx = rem & 31, by = (rem >> 5) & 15;
    const float* src;
    uint16_t* dst;
    int N;
    if (z == 0) { src = w_kv; dst = wkvT; N = 2048; }
    else if (z == 1) { src = w_q; dst = wqT; N = 1024; }
    else { src = w_proj; dst = wpT; N = 1024; }
    const int n0 = bx * 64;
    if (n0 >= N) return;
    const int k0 = by * 64;
#pragma unroll
    for (int it = 0; it < 16; ++it) {
      int idx = it * 256 + tid;
      int r = idx >> 6, c = idx & 63;
      tile[r][c] = f2bf(src[(size_t)(k0 + r) * N + n0 + c]);
    }
    __syncthreads();
#pragma unroll
    for (int it = 0; it < 16; ++it) {
      int idx = it * 256 + tid;
      int r = idx >> 6, c = idx & 63;
      dst[(size_t)(n0 + r) * 1024 + k0 + c] = tile[c][r];
    }
  }
}

// ---------------- aux_mm: q-proj (blocks 0..127) + gate GEMV (blocks 128..255) ----------------

__global__ __launch_bounds__(256) void aux_mm_kernel(
    const uint16_t* __restrict__ ch, const uint16_t* __restrict__ wqT,
    uint16_t* __restrict__ qbf, const uint16_t* __restrict__ xh,
    const float* __restrict__ wla, float* __restrict__ gv) {
  __shared__ __align__(16) uint16_t smem[16 * 1024];  // 32 KB union
  const int tid = threadIdx.x;
  const int wv = tid >> 6;
  const int lane = tid & 63;
  const int lr = lane & 15;
  const int lh = lane >> 4;

  if (blockIdx.x < 128) {
    uint16_t* sA = smem;
    uint16_t* sB = smem + 128 * 32;
    const int wm = wv >> 1, wn = wv & 1;
    const int rowBase = (blockIdx.x & 15) * 128;
    const int colBase = (blockIdx.x >> 4) * 128;

    f32x4 zero4 = {0.f, 0.f, 0.f, 0.f};
    f32x4 acc[4][4];
#pragma unroll
    for (int m = 0; m < 4; ++m)
#pragma unroll
      for (int n = 0; n < 4; ++n) acc[m][n] = zero4;

    for (int k0 = 0; k0 < 1024; k0 += 32) {
#pragma unroll
      for (int it = 0; it < 2; ++it) {
        int s = it * 256 + tid;
        int row = s >> 2, cc = s & 3;
        int sc = cc ^ ((row >> 1) & 3);
        GLD16(ch + (size_t)(rowBase + row) * 1024 + k0 + sc * 8,
              sA + ((size_t)it * 256 + wv * 64) * 8);
        GLD16(wqT + (size_t)(colBase + row) * 1024 + k0 + sc * 8,
              sB + ((size_t)it * 256 + wv * 64) * 8);
      }
      __syncthreads();
      bf16x8 af[4], bfr[4];
#pragma unroll
      for (int m = 0; m < 4; ++m) {
        int r = wm * 64 + m * 16 + lr;
        af[m] = *(const bf16x8*)&sA[r * 32 + ((lh ^ ((r >> 1) & 3)) << 3)];
      }
#pragma unroll
      for (int n = 0; n < 4; ++n) {
        int r = wn * 64 + n * 16 + lr;
        bfr[n] = *(const bf16x8*)&sB[r * 32 + ((lh ^ ((r >> 1) & 3)) << 3)];
      }
#pragma unroll
      for (int m = 0; m < 4; ++m)
#pragma unroll
        for (int n = 0; n < 4; ++n)
          acc[m][n] = __builtin_amdgcn_mfma_f32_16x16x32_bf16(af[m], bfr[n],
                                                              acc[m][n], 0, 0, 0);
      __syncthreads();
    }

#pragma unroll
    for (int m = 0; m < 4; ++m) {
      int gr0 = rowBase + wm * 64 + m * 16 + lh * 4;
      int b = gr0 >> 9, nq0 = gr0 & 511;
#pragma unroll
      for (int n = 0; n < 4; ++n) {
        int gc = colBase + wn * 64 + n * 16 + lr;
        int hh = gc >> 6, d = gc & 63;
        size_t base = (((size_t)b * NH + hh) * NQ + nq0) * DH + d;
#pragma unroll
        for (int j = 0; j < 4; ++j)
          qbf[base + (size_t)j * DH] = f2bf(acc[m][n][j] * 0.125f);
      }
    }
  } else {
    uint16_t* sW = smem;
#pragma unroll
    for (int it = 0; it < 64; ++it) {
      int i = it * 256 + tid;
      int c = i >> 4, h = i & 15;
      sW[h * 1024 + (((c >> 3) ^ (h & 7)) << 3) + (c & 7)] = f2bf(wla[i]);
    }
    __syncthreads();

    const int rb = (blockIdx.x - 128) * 64 + wv * 16;
    f32x4 acc = {0.f, 0.f, 0.f, 0.f};
    for (int t = 0; t < 32; ++t) {
      bf16x8 af = *(const bf16x8*)&xh[(size_t)(rb + lr) * 1024 + t * 32 + lh * 8];
      bf16x8 bf = *(const bf16x8*)&sW[lr * 1024 + (((t * 4 + lh) ^ (lr & 7)) << 3)];
      acc = __builtin_amdgcn_mfma_f32_16x16x32_bf16(af, bf, acc, 0, 0, 0);
    }
    int nxg = rb + lh * 4;
    int b = nxg >> 11, nx = nxg & 2047;
    float4 st = {acc[0], acc[1], acc[2], acc[3]};
    *(float4*)&gv[((size_t)b * NH + lr) * NX + nx] = st;
  }
}

// ---------------- 8-phase 256x256 GEMM for x@w_kv (round-8 proven, 256 blocks = 1/CU) ----------------

__global__ __launch_bounds__(512, 2) void gemm_kv8(
    const uint16_t* __restrict__ A, const uint16_t* __restrict__ BT,
    uint16_t* __restrict__ outK, uint16_t* __restrict__ outV) {
  __shared__ __align__(16) uint16_t lds[65536];  // [buf][A|B][256][64]

  const int tid = threadIdx.x;
  const int wid = tid >> 6;
  const int lane = tid & 63;
  const int lr = lane & 15;
  const int lh = lane >> 4;
  const int wm = wid >> 2;
  const int wn = wid & 3;
  const int rowBase = blockIdx.x * 256;
  const int colBase = blockIdx.y * 256;

  f32x4 acc[8][4];
#pragma unroll
  for (int m = 0; m < 8; ++m)
#pragma unroll
    for (int n = 0; n < 4; ++n) acc[m][n] = (f32x4){0.f, 0.f, 0.f, 0.f};

  auto stageB = [&](int T, int h) {
    const uint16_t* srcp = BT + (size_t)(colBase + h * 128) * 1024 + T * 64;
    uint16_t* dst = lds + ((T & 1) * 32768 + 16384 + h * 8192);
#pragma unroll
    for (int it = 0; it < 2; ++it) {
      int s = it * 512 + tid;
      int row = s >> 3, cc = s & 7;
      int sc = cc ^ (row & 7);
      GLD16(srcp + (size_t)row * 1024 + sc * 8,
            dst + ((size_t)it * 512 + wid * 64) * 8);
    }
  };
  auto stageA012 = [&](int T) {
    const uint16_t* srcp = A + (size_t)rowBase * 1024 + T * 64;
    uint16_t* dstbase = lds + (T & 1) * 32768;
    int r64 = tid >> 3, cc = tid & 7;
#pragma unroll
    for (int st = 0; st < 3; ++st) {
      int rloc = (r64 < 32) ? (st * 32 + r64) : (96 + st * 32 + r64);
      int sc = cc ^ (rloc & 7);
      int wrow = (wid < 4) ? (st * 32 + wid * 8) : (128 + st * 32 + (wid - 4) * 8);
      GLD16(srcp + (size_t)rloc * 1024 + sc * 8, dstbase + (size_t)wrow * 64);
    }
  };
  auto stageA3 = [&](int T) {
    const uint16_t* srcp = A + (size_t)rowBase * 1024 + T * 64;
    uint16_t* dstbase = lds + (T & 1) * 32768;
    int r64 = tid >> 3, cc = tid & 7;
    int rloc = (r64 < 32) ? (96 + r64) : (192 + r64);
    int sc = cc ^ (rloc & 7);
    int wrow = (wid < 4) ? (96 + wid * 8) : (224 + (wid - 4) * 8);
    GLD16(srcp + (size_t)rloc * 1024 + sc * 8, dstbase + (size_t)wrow * 64);
  };

  auto rdA = [&](int p, int m, int kk) -> bf16x8 {
    int r = wm * 128 + m * 16 + lr;
    return *(const bf16x8*)&lds[p * 32768 + r * 64 +
                                (((kk * 4 + lh) ^ (r & 7)) << 3)];
  };
  auto rdB = [&](int p, int n, int kk) -> bf16x8 {
    int r = wn * 64 + n * 16 + lr;
    return *(const bf16x8*)&lds[p * 32768 + 16384 + r * 64 +
                                (((kk * 4 + lh) ^ (r & 7)) << 3)];
  };

  auto tile4 = [&](int t, bool last) {
    const int p = t & 1;
    bf16x8 b[4][2], a0[2], a1[2];
#pragma unroll
    for (int q = 0; q < 4; ++q) {
      if (q == 0) {
#pragma unroll
        for (int n = 0; n < 4; ++n)
#pragma unroll
          for (int kk = 0; kk < 2; ++kk) b[n][kk] = rdB(p, n, kk);
      }
#pragma unroll
      for (int kk = 0; kk < 2; ++kk) {
        a0[kk] = rdA(p, 2 * q, kk);
        a1[kk] = rdA(p, 2 * q + 1, kk);
      }
      if (q == 0) {
        stageA3(t + 1);
      } else if (q == 1) {
        if (!last) stageB(t + 2, 0);
      } else if (q == 2) {
        if (!last) stageB(t + 2, 1);
      } else {
        if (!last) stageA012(t + 2);
        if (last)
          asm volatile("s_waitcnt vmcnt(0)" ::: "memory");
        else
          asm volatile("s_waitcnt vmcnt(7)" ::: "memory");
      }
      __builtin_amdgcn_s_barrier();
      asm volatile("s_waitcnt lgkmcnt(0)" ::: "memory");
      __builtin_amdgcn_sched_barrier(0);
      __builtin_amdgcn_s_setprio(1);
#pragma unroll
      for (int n = 0; n < 4; ++n)
#pragma unroll
        for (int kk = 0; kk < 2; ++kk) {
          acc[2 * q][n] = __builtin_amdgcn_mfma_f32_16x16x32_bf16(
              a0[kk], b[n][kk], acc[2 * q][n], 0, 0, 0);
          acc[2 * q + 1][n] = __builtin_amdgcn_mfma_f32_16x16x32_bf16(
              a1[kk], b[n][kk], acc[2 * q + 1][n], 0, 0, 0);
        }
      __builtin_amdgcn_s_setprio(0);
      __builtin_amdgcn_s_barrier();
      asm volatile("" ::: "memory");
    }
  };

  auto tileEpi = [&](int t) {
    const int p = t & 1;
    bf16x8 b[4][2], a0[2], a1[2];
#pragma unroll
    for (int n = 0; n < 4; ++n)
#pragma unroll
      for (int kk = 0; kk < 2; ++kk) b[n][kk] = rdB(p, n, kk);
#pragma unroll
    for (int q = 0; q < 4; ++q) {
#pragma unroll
      for (int kk = 0; kk < 2; ++kk) {
        a0[kk] = rdA(p, 2 * q, kk);
        a1[kk] = rdA(p, 2 * q + 1, kk);
      }
#pragma unroll
      for (int n = 0; n < 4; ++n)
#pragma unroll
        for (int kk = 0; kk < 2; ++kk) {
          acc[2 * q][n] = __builtin_amdgcn_mfma_f32_16x16x32_bf16(
              a0[kk], b[n][kk], acc[2 * q][n], 0, 0, 0);
          acc[2 * q + 1][n] = __builtin_amdgcn_mfma_f32_16x16x32_bf16(
              a1[kk], b[n][kk], acc[2 * q + 1][n], 0, 0, 0);
        }
    }
  };

  stageB(0, 0); stageB(0, 1); stageA012(0); stageA3(0);
  stageB(1, 0); stageB(1, 1); stageA012(1);
  asm volatile("s_waitcnt vmcnt(7)" ::: "memory");
  __builtin_amdgcn_s_barrier();

  for (int t = 0; t < 14; ++t) tile4(t, false);
  tile4(14, true);
  tileEpi(15);

#pragma unroll
  for (int m = 0; m < 8; ++m) {
    int gr0 = rowBase + wm * 128 + m * 16 + lh * 4;
    int b_ = gr0 >> 11, nx0 = gr0 & 2047;
#pragma unroll
    for (int n = 0; n < 4; ++n) {
      int gc = colBase + wn * 64 + n * 16 + lr;
      if (gc < 1024) {
        int hh = gc >> 6, d = gc & 63;
        size_t base = (((size_t)b_ * NH + hh) * NX + nx0) * DH + d;
#pragma unroll
        for (int j = 0; j < 4; ++j)
          outK[base + (size_t)j * DH] = f2bf(acc[m][n][j]);
      } else {
        int c2 = gc - 1024;
        int hh = c2 >> 6, d = c2 & 63;
        ushort4 pv;
        pv.x = f2bf(acc[m][n][0]);
        pv.y = f2bf(acc[m][n][1]);
        pv.z = f2bf(acc[m][n][2]);
        pv.w = f2bf(acc[m][n][3]);
        *(ushort4*)&outV[(((size_t)b_ * NH + hh) * DH + d) * NX + nx0] = pv;
      }
    }
  }
}

// ---------------- gemm_proj: 64x128 tiles, 256 blocks (full CU fill) ----------------
// ctx@w_proj + bias -> out fp32. Grid (32,8): id = bx + 32*by ≡ bx mod 8 ->
// A-row-panel locality per XCD. Waves 2Mx2N, each 32x64 (acc[2][4]).

__global__ __launch_bounds__(256) void gemm_proj(
    const uint16_t* __restrict__ A, const uint16_t* __restrict__ BT,
    float* __restrict__ outF, const float* __restrict__ bias) {
  constexpr int K = 1024;
  __shared__ __align__(16) uint16_t sA[64 * 32];
  __shared__ __align__(16) uint16_t sB[128 * 32];

  const int tid = threadIdx.x;
  const int wv = tid >> 6;
  const int lane = tid & 63;
  const int lr = lane & 15;
  const int lh = lane >> 4;
  const int wm = wv >> 1, wn = wv & 1;
  const int rowBase = blockIdx.x * 64;
  const int colBase = blockIdx.y * 128;

  f32x4 zero4 = {0.f, 0.f, 0.f, 0.f};
  f32x4 acc[2][4];
#pragma unroll
  for (int m = 0; m < 2; ++m)
#pragma unroll
    for (int n = 0; n < 4; ++n) acc[m][n] = zero4;

  for (int k0 = 0; k0 < K; k0 += 32) {
    {  // A: 64x32, 1 load/thread
      int row = tid >> 2, cc = tid & 3;
      int sc = cc ^ ((row >> 1) & 3);
      GLD16(A + (size_t)(rowBase + row) * K + k0 + sc * 8,
            sA + ((size_t)wv * 64) * 8);
    }
#pragma unroll
    for (int it = 0; it < 2; ++it) {  // B: 128x32, 2 loads/thread
      int s = it * 256 + tid;
      int row = s >> 2, cc = s & 3;
      int sc = cc ^ ((row >> 1) & 3);
      GLD16(BT + (size_t)(colBase + row) * K + k0 + sc * 8,
            sB + ((size_t)it * 256 + wv * 64) * 8);
    }
    __syncthreads();
    bf16x8 af[2], bfr[4];
#pragma unroll
    for (int m = 0; m < 2; ++m) {
      int r = wm * 32 + m * 16 + lr;
      af[m] = *(const bf16x8*)&sA[r * 32 + ((lh ^ ((r >> 1) & 3)) << 3)];
    }
#pragma unroll
    for (int n = 0; n < 4; ++n) {
      int r = wn * 64 + n * 16 + lr;
      bfr[n] = *(const bf16x8*)&sB[r * 32 + ((lh ^ ((r >> 1) & 3)) << 3)];
    }
#pragma unroll
    for (int m = 0; m < 2; ++m)
#pragma unroll
      for (int n = 0; n < 4; ++n)
        acc[m][n] = __builtin_amdgcn_mfma_f32_16x16x32_bf16(af[m], bfr[n],
                                                            acc[m][n], 0, 0, 0);
    __syncthreads();
  }

#pragma unroll
  for (int m = 0; m < 2; ++m) {
    int gr0 = rowBase + wm * 32 + m * 16 + lh * 4;
#pragma unroll
    for (int n = 0; n < 4; ++n) {
      int gc = colBase + wn * 64 + n * 16 + lr;
      float bi = bias[gc];
#pragma unroll
      for (int j = 0; j < 4; ++j)
        outF[(size_t)(gr0 + j) * 1024 + gc] = acc[m][n][j] + bi;
    }
  }
}

// ---------------- gatev: gate reduce (blocks 0..63) + vcolsum (blocks 64..319) ----------------

__global__ __launch_bounds__(256) void gatev_kernel(
    const float* __restrict__ gv, float* __restrict__ gate,
    const uint16_t* __restrict__ VT, float* __restrict__ vcs) {
  const int tid = threadIdx.x;
  const int wv = tid >> 6, lane = tid & 63;
  if (blockIdx.x < 64) {
    const int bh = blockIdx.x;
    const float* p = gv + (size_t)bh * NX;
    float s = 0.f, mx = -1e30f;
    for (int i = tid; i < NX; i += 256) {
      float v = p[i];
      s += v;
      mx = fmaxf(mx, v);
    }
#pragma unroll
    for (int off = 1; off < 64; off <<= 1) {
      s += __shfl_xor(s, off, 64);
      mx = fmaxf(mx, __shfl_xor(mx, off, 64));
    }
    __shared__ float ss[4], sm[4];
    if (lane == 0) { ss[wv] = s; sm[wv] = mx; }
    __syncthreads();
    if (tid == 0) {
      float S = ss[0] + ss[1] + ss[2] + ss[3];
      float M = fmaxf(fmaxf(sm[0], sm[1]), fmaxf(sm[2], sm[3]));
      gate[bh] = 0.5f * (S / (float)NX) + 0.5f * M;
    }
  } else {
    const int idx = blockIdx.x - 64;  // 0..255
    const int bh = idx & 63, quarter = idx >> 6;
#pragma unroll
    for (int dd = 0; dd < 4; ++dd) {
      int d = quarter * 16 + dd * 4 + wv;
      const uint16_t* row = VT + ((size_t)bh * DH + d) * NX;
      float s = 0.f;
#pragma unroll
      for (int i = 0; i < 4; ++i) {
        bf16x8 v = *(const bf16x8*)&row[(i * 64 + lane) * 8];
#pragma unroll
        for (int j = 0; j < 8; ++j) s += (float)v[j];
      }
#pragma unroll
      for (int off = 1; off < 64; off <<= 1) s += __shfl_xor(s, off, 64);
      if (lane == 0) vcs[bh * DH + d] = s;
    }
  }
}

// ---------------- attention: single-pass flash, dbuf K/V + T5 setprio ----------------
// Round-15: round-14 structure + s_setprio(1) around both MFMA clusters
// (m191: setprio helps attn when waves are at different phases — which the
// barrier-free mid-tile created). Sync structure unchanged from round 14.

__global__ __launch_bounds__(256) void attn_kernel(
    const uint16_t* __restrict__ Q, const uint16_t* __restrict__ K,
    const uint16_t* __restrict__ VT, const float* __restrict__ gate,
    const float* __restrict__ attw, const float* __restrict__ vcs,
    uint16_t* __restrict__ ctxh) {
  __shared__ __align__(16) uint16_t sK[2][128 * 64];
  __shared__ __align__(16) uint16_t sV[2][64 * 128];
  __shared__ __align__(16) __bf16 sPe[64 * 128];

  const int tid = threadIdx.x;
  const int wv = tid >> 6;
  const int lane = tid & 63;
  const int lr = lane & 15;
  const int lh = lane >> 4;
  const int bh = blockIdx.x;
  const int q0 = blockIdx.y * 64;
  const float g = gate[bh];
  const float w = attw[0];

  const uint16_t* Qb = Q + ((size_t)bh * NQ + q0) * DH;
  const uint16_t* Kb = K + (size_t)bh * NX * DH;
  const uint16_t* Vb = VT + (size_t)bh * DH * NX;

  auto stageKV = [&](int kt, int p) {  // 8 loads/thread
#pragma unroll
    for (int it = 0; it < 4; ++it) {
      int s = it * 256 + tid;
      int row = s >> 3, cc = s & 7;
      int sc = cc ^ (row & 7);
      GLD16(Kb + (size_t)(kt * 128 + row) * DH + sc * 8,
            sK[p] + ((size_t)it * 256 + wv * 64) * 8);
    }
#pragma unroll
    for (int it = 0; it < 4; ++it) {
      int s = it * 256 + tid;
      int row = s >> 4, cc = s & 15;
      int sc = cc ^ (row & 15);
      GLD16(Vb + (size_t)row * NX + kt * 128 + sc * 8,
            sV[p] + ((size_t)it * 256 + wv * 64) * 8);
    }
  };

  bf16x8 qa[2];
#pragma unroll
  for (int kk = 0; kk < 2; ++kk)
    qa[kk] = *(const bf16x8*)&Qb[(wv * 16 + lr) * DH + kk * 32 + lh * 8];

  float lp[4] = {0.f, 0.f, 0.f, 0.f};
  f32x4 zero4 = {0.f, 0.f, 0.f, 0.f};
  f32x4 accp[4];
#pragma unroll
  for (int d = 0; d < 4; ++d) accp[d] = zero4;

  stageKV(0, 0);  // prologue

  for (int kt = 0; kt < 16; ++kt) {
    const int p = kt & 1;
    if (kt < 15) {
      stageKV(kt + 1, p ^ 1);
      asm volatile("s_waitcnt vmcnt(8)" ::: "memory");
    } else {
      asm volatile("s_waitcnt vmcnt(0)" ::: "memory");
    }
    __builtin_amdgcn_s_barrier();  // tile kt's K/V visible to all waves
    __builtin_amdgcn_s_setprio(1);
#pragma unroll
    for (int n = 0; n < 8; ++n) {
      f32x4 a4 = {0.f, 0.f, 0.f, 0.f};
      int r = n * 16 + lr;
#pragma unroll
      for (int kk = 0; kk < 2; ++kk) {
        bf16x8 kb =
            *(const bf16x8*)&sK[p][r * 64 + (((kk * 4 + lh) ^ (r & 7)) << 3)];
        a4 = __builtin_amdgcn_mfma_f32_16x16x32_bf16(qa[kk], kb, a4, 0, 0, 0);
      }
      __builtin_amdgcn_s_setprio(0);
#pragma unroll
      for (int j = 0; j < 4; ++j) {
        float e = __expf(a4[j]);
        lp[j] += e;
        int qr = wv * 16 + lh * 4 + j;
        int key = n * 16 + lr;
        int idx = qr * 128 + ((((key >> 3) ^ (qr & 15))) << 3) + (key & 7);
        sPe[idx] = (__bf16)e;
      }
      __builtin_amdgcn_s_setprio(1);
    }
    __builtin_amdgcn_s_setprio(0);
    // sPe is wave-private: wave-local ordering only (no block barrier).
    asm volatile("s_waitcnt lgkmcnt(0)" ::: "memory");
    __builtin_amdgcn_sched_barrier(0);
    const int prow = wv * 16 + lr;
    __builtin_amdgcn_s_setprio(1);
#pragma unroll
    for (int kk = 0; kk < 4; ++kk) {
      int pidx = prow * 128 + (((kk * 4 + lh) ^ (prow & 15)) << 3);
      bf16x8 pe = *(const bf16x8*)&sPe[pidx];
#pragma unroll
      for (int df = 0; df < 4; ++df) {
        int vr = df * 16 + lr;
        bf16x8 vb =
            *(const bf16x8*)&sV[p][vr * 128 + (((kk * 4 + lh) ^ (vr & 15)) << 3)];
        accp[df] = __builtin_amdgcn_mfma_f32_16x16x32_bf16(pe, vb, accp[df], 0, 0, 0);
      }
    }
    __builtin_amdgcn_s_setprio(0);
    asm volatile("s_waitcnt lgkmcnt(0)" ::: "memory");
    __builtin_amdgcn_s_barrier();  // all waves done reading buf p before restage
  }
#pragma unroll
  for (int off = 1; off < 16; off <<= 1)
#pragma unroll
    for (int j = 0; j < 4; ++j) lp[j] += __shfl_xor(lp[j], off, 64);

  const int b = bh >> 4, h = bh & 15;
  const float c1 = w / ((float)NX + g);
  const float c2 = w * g / ((float)NX + g) + (1.f - w);
  float rl[4];
#pragma unroll
  for (int j = 0; j < 4; ++j) rl[j] = 1.f / lp[j];
#pragma unroll
  for (int df = 0; df < 4; ++df) {
    int d = df * 16 + lr;
    float cv = vcs[bh * DH + d];
#pragma unroll
    for (int j = 0; j < 4; ++j) {
      int qr = q0 + wv * 16 + lh * 4 + j;
      float p = accp[df][j] * rl[j];
      ctxh[(((size_t)b * NQ + qr) * NH + h) * DH + d] = f2bf(c1 * cv + c2 * p);
    }
  }
}

// ---------------- launch ----------------

extern "C" void kernel_launch(void* const* d_in, const int* in_sizes, int n_in,
                              void* d_out, int out_size, void* d_ws,
                              size_t ws_size, hipStream_t stream) {
  const float* x = (const float*)d_in[0];
  const float* cls = (const float*)d_in[1];
  const float* w_kv = (const float*)d_in[2];
  const float* w_q = (const float*)d_in[3];
  const float* w_la = (const float*)d_in[4];
  const float* w_proj = (const float*)d_in[5];
  const float* b_proj = (const float*)d_in[6];
  const float* att_w = (const float*)d_in[7];
  float* out = (float*)d_out;

  char* ws = (char*)d_ws;
  size_t off = 0;
  auto alloc = [&](size_t bytes) {
    void* p = ws + off;
    off += (bytes + 255) & ~(size_t)255;
    return p;
  };
  uint16_t* xh = (uint16_t*)alloc(4ull * NX * CDIM * 2);
  uint16_t* ch = (uint16_t*)alloc(4ull * NQ * CDIM * 2);
  uint16_t* wkvT = (uint16_t*)alloc(2048ull * 1024 * 2);
  uint16_t* wqT = (uint16_t*)alloc(1024ull * 1024 * 2);
  uint16_t* wpT = (uint16_t*)alloc(1024ull * 1024 * 2);
  uint16_t* kbf = (uint16_t*)alloc(4ull * NH * NX * DH * 2);
  uint16_t* vT = (uint16_t*)alloc(4ull * NH * DH * NX * 2);
  uint16_t* qbf = (uint16_t*)alloc(4ull * NH * NQ * DH * 2);
  float* gv = (float*)alloc(4ull * NH * NX * 4);
  float* gate = (float*)alloc(1024);
  float* vcs = (float*)alloc(4ull * NH * DH * 4);
  uint16_t* ctxh = (uint16_t*)alloc(4ull * NQ * CDIM * 2);

  prep_kernel<<<3584, 256, 0, stream>>>(x, xh, cls, ch, w_kv, wkvT, w_q, wqT,
                                        w_proj, wpT);

  aux_mm_kernel<<<256, 256, 0, stream>>>(ch, wqT, qbf, xh, w_la, gv);
  gemm_kv8<<<dim3(32, 8), 512, 0, stream>>>(xh, wkvT, kbf, vT);

  gatev_kernel<<<320, 256, 0, stream>>>(gv, gate, vT, vcs);

  attn_kernel<<<dim3(64, 8), 256, 0, stream>>>(qbf, kbf, vT, gate, att_w, vcs, ctxh);

  gemm_proj<<<dim3(32, 8), 256, 0, stream>>>(ctxh, wpT, out, b_proj);
}

// Round 16
// 131.867 us; speedup vs baseline: 1.1510x; 1.0175x over previous
//
#include <hip/hip_runtime.h>
#include <stdint.h>

#define NX 2048
#define NQ 512
#define CDIM 1024
#define NH 16
#define DH 64

typedef __attribute__((ext_vector_type(8))) __bf16 bf16x8;
typedef __attribute__((ext_vector_type(4))) float f32x4;

__device__ __forceinline__ uint16_t f2bf(float f) {
  uint32_t i = __float_as_uint(f);
  uint32_t r = i + 0x7fffu + ((i >> 16) & 1u);
  return (uint16_t)(r >> 16);
}

#define GLD16(g, l)                                                            \
  __builtin_amdgcn_global_load_lds(                                            \
      (const __attribute__((address_space(1))) uint32_t*)(g),                  \
      (__attribute__((address_space(3))) uint32_t*)(l), 16, 0, 0)

// ---------------- prep: casts (x,cls) + weight transposes, one launch ----------------

__global__ __launch_bounds__(256) void prep_kernel(
    const float* __restrict__ x, uint16_t* __restrict__ xh,
    const float* __restrict__ cls, uint16_t* __restrict__ ch,
    const float* __restrict__ w_kv, uint16_t* __restrict__ wkvT,
    const float* __restrict__ w_q, uint16_t* __restrict__ wqT,
    const float* __restrict__ w_proj, uint16_t* __restrict__ wpT) {
  __shared__ uint16_t tile[64][65];
  const int tid = threadIdx.x;
  const int bid = blockIdx.x;
  if (bid < 2048) {
    const int n40 = 4 * NX * CDIM / 4, n41 = 4 * NQ * CDIM / 4;
    const int ntot = n40 + n41;
    const int stride = 2048 * 256;
    for (int i = bid * 256 + tid; i < ntot; i += stride) {
      if (i < n40) {
        float4 v = ((const float4*)x)[i];
        ushort4 o;
        o.x = f2bf(v.x); o.y = f2bf(v.y); o.z = f2bf(v.z); o.w = f2bf(v.w);
        ((ushort4*)xh)[i] = o;
      } else {
        float4 v = ((const float4*)cls)[i - n40];
        ushort4 o;
        o.x = f2bf(v.x); o.y = f2bf(v.y); o.z = f2bf(v.z); o.w = f2bf(v.w);
        ((ushort4*)ch)[i - n40] = o;
      }
    }
  } else {
    const int rem = bid - 2048;          // 0..1535
    const int z = rem >> 9;              // 0..2
    const int bx = rem & 31, by = (rem >> 5) & 15;
    const float* src;
    uint16_t* dst;
    int N;
    if (z == 0) { src = w_kv; dst = wkvT; N = 2048; }
    else if (z == 1) { src = w_q; dst = wqT; N = 1024; }
    else { src = w_proj; dst = wpT; N = 1024; }
    const int n0 = bx * 64;
    if (n0 >= N) return;
    const int k0 = by * 64;
#pragma unroll
    for (int it = 0; it < 16; ++it) {
      int idx = it * 256 + tid;
      int r = idx >> 6, c = idx & 63;
      tile[r][c] = f2bf(src[(size_t)(k0 + r) * N + n0 + c]);
    }
    __syncthreads();
#pragma unroll
    for (int it = 0; it < 16; ++it) {
      int idx = it * 256 + tid;
      int r = idx >> 6, c = idx & 63;
      dst[(size_t)(n0 + r) * 1024 + k0 + c] = tile[c][r];
    }
  }
}

// ---------------- aux_mm v2: q-proj 64x128 tiles (blocks 0..255, full CU fill)
//                  + gate GEMV tail (blocks 256..383) ----------------
// q-proj: cls@wqT -> q [B,H,N,D] * 0.125. rowBase=(bid&31)*64 keeps A-row-
// panel per XCD (id%8 = bid%8... within the 256 q-blocks). Body = proven
// gemm_proj structure (2Mx2N waves, acc[2][4], chunk-XOR swizzle).

__global__ __launch_bounds__(256) void aux_mm_kernel(
    const uint16_t* __restrict__ ch, const uint16_t* __restrict__ wqT,
    uint16_t* __restrict__ qbf, const uint16_t* __restrict__ xh,
    const float* __restrict__ wla, float* __restrict__ gv) {
  __shared__ __align__(16) uint16_t smem[16 * 1024];  // 32 KB union
  const int tid = threadIdx.x;
  const int wv = tid >> 6;
  const int lane = tid & 63;
  const int lr = lane & 15;
  const int lh = lane >> 4;

  if (blockIdx.x < 256) {
    uint16_t* sA = smem;              // 64*32
    uint16_t* sB = smem + 64 * 32;    // 128*32
    const int wm = wv >> 1, wn = wv & 1;
    const int rowBase = (blockIdx.x & 31) * 64;
    const int colBase = (blockIdx.x >> 5) * 128;

    f32x4 zero4 = {0.f, 0.f, 0.f, 0.f};
    f32x4 acc[2][4];
#pragma unroll
    for (int m = 0; m < 2; ++m)
#pragma unroll
      for (int n = 0; n < 4; ++n) acc[m][n] = zero4;

    for (int k0 = 0; k0 < 1024; k0 += 32) {
      {  // A: 64x32, 1 load/thread
        int row = tid >> 2, cc = tid & 3;
        int sc = cc ^ ((row >> 1) & 3);
        GLD16(ch + (size_t)(rowBase + row) * 1024 + k0 + sc * 8,
              sA + ((size_t)wv * 64) * 8);
      }
#pragma unroll
      for (int it = 0; it < 2; ++it) {  // B: 128x32, 2 loads/thread
        int s = it * 256 + tid;
        int row = s >> 2, cc = s & 3;
        int sc = cc ^ ((row >> 1) & 3);
        GLD16(wqT + (size_t)(colBase + row) * 1024 + k0 + sc * 8,
              sB + ((size_t)it * 256 + wv * 64) * 8);
      }
      __syncthreads();
      bf16x8 af[2], bfr[4];
#pragma unroll
      for (int m = 0; m < 2; ++m) {
        int r = wm * 32 + m * 16 + lr;
        af[m] = *(const bf16x8*)&sA[r * 32 + ((lh ^ ((r >> 1) & 3)) << 3)];
      }
#pragma unroll
      for (int n = 0; n < 4; ++n) {
        int r = wn * 64 + n * 16 + lr;
        bfr[n] = *(const bf16x8*)&sB[r * 32 + ((lh ^ ((r >> 1) & 3)) << 3)];
      }
#pragma unroll
      for (int m = 0; m < 2; ++m)
#pragma unroll
        for (int n = 0; n < 4; ++n)
          acc[m][n] = __builtin_amdgcn_mfma_f32_16x16x32_bf16(af[m], bfr[n],
                                                              acc[m][n], 0, 0, 0);
      __syncthreads();
    }

#pragma unroll
    for (int m = 0; m < 2; ++m) {
      int gr0 = rowBase + wm * 32 + m * 16 + lh * 4;
      int b = gr0 >> 9, nq0 = gr0 & 511;
#pragma unroll
      for (int n = 0; n < 4; ++n) {
        int gc = colBase + wn * 64 + n * 16 + lr;
        int hh = gc >> 6, d = gc & 63;
        size_t base = (((size_t)b * NH + hh) * NQ + nq0) * DH + d;
#pragma unroll
        for (int j = 0; j < 4; ++j)
          qbf[base + (size_t)j * DH] = f2bf(acc[m][n][j] * 0.125f);
      }
    }
  } else {
    uint16_t* sW = smem;
#pragma unroll
    for (int it = 0; it < 64; ++it) {
      int i = it * 256 + tid;
      int c = i >> 4, h = i & 15;
      sW[h * 1024 + (((c >> 3) ^ (h & 7)) << 3) + (c & 7)] = f2bf(wla[i]);
    }
    __syncthreads();

    const int rb = (blockIdx.x - 256) * 64 + wv * 16;
    f32x4 acc = {0.f, 0.f, 0.f, 0.f};
    for (int t = 0; t < 32; ++t) {
      bf16x8 af = *(const bf16x8*)&xh[(size_t)(rb + lr) * 1024 + t * 32 + lh * 8];
      bf16x8 bf = *(const bf16x8*)&sW[lr * 1024 + (((t * 4 + lh) ^ (lr & 7)) << 3)];
      acc = __builtin_amdgcn_mfma_f32_16x16x32_bf16(af, bf, acc, 0, 0, 0);
    }
    int nxg = rb + lh * 4;
    int b = nxg >> 11, nx = nxg & 2047;
    float4 st = {acc[0], acc[1], acc[2], acc[3]};
    *(float4*)&gv[((size_t)b * NH + lr) * NX + nx] = st;
  }
}

// ---------------- 8-phase 256x256 GEMM for x@w_kv (round-8 proven, 256 blocks = 1/CU) ----------------

__global__ __launch_bounds__(512, 2) void gemm_kv8(
    const uint16_t* __restrict__ A, const uint16_t* __restrict__ BT,
    uint16_t* __restrict__ outK, uint16_t* __restrict__ outV) {
  __shared__ __align__(16) uint16_t lds[65536];  // [buf][A|B][256][64]

  const int tid = threadIdx.x;
  const int wid = tid >> 6;
  const int lane = tid & 63;
  const int lr = lane & 15;
  const int lh = lane >> 4;
  const int wm = wid >> 2;
  const int wn = wid & 3;
  const int rowBase = blockIdx.x * 256;
  const int colBase = blockIdx.y * 256;

  f32x4 acc[8][4];
#pragma unroll
  for (int m = 0; m < 8; ++m)
#pragma unroll
    for (int n = 0; n < 4; ++n) acc[m][n] = (f32x4){0.f, 0.f, 0.f, 0.f};

  auto stageB = [&](int T, int h) {
    const uint16_t* srcp = BT + (size_t)(colBase + h * 128) * 1024 + T * 64;
    uint16_t* dst = lds + ((T & 1) * 32768 + 16384 + h * 8192);
#pragma unroll
    for (int it = 0; it < 2; ++it) {
      int s = it * 512 + tid;
      int row = s >> 3, cc = s & 7;
      int sc = cc ^ (row & 7);
      GLD16(srcp + (size_t)row * 1024 + sc * 8,
            dst + ((size_t)it * 512 + wid * 64) * 8);
    }
  };
  auto stageA012 = [&](int T) {
    const uint16_t* srcp = A + (size_t)rowBase * 1024 + T * 64;
    uint16_t* dstbase = lds + (T & 1) * 32768;
    int r64 = tid >> 3, cc = tid & 7;
#pragma unroll
    for (int st = 0; st < 3; ++st) {
      int rloc = (r64 < 32) ? (st * 32 + r64) : (96 + st * 32 + r64);
      int sc = cc ^ (rloc & 7);
      int wrow = (wid < 4) ? (st * 32 + wid * 8) : (128 + st * 32 + (wid - 4) * 8);
      GLD16(srcp + (size_t)rloc * 1024 + sc * 8, dstbase + (size_t)wrow * 64);
    }
  };
  auto stageA3 = [&](int T) {
    const uint16_t* srcp = A + (size_t)rowBase * 1024 + T * 64;
    uint16_t* dstbase = lds + (T & 1) * 32768;
    int r64 = tid >> 3, cc = tid & 7;
    int rloc = (r64 < 32) ? (96 + r64) : (192 + r64);
    int sc = cc ^ (rloc & 7);
    int wrow = (wid < 4) ? (96 + wid * 8) : (224 + (wid - 4) * 8);
    GLD16(srcp + (size_t)rloc * 1024 + sc * 8, dstbase + (size_t)wrow * 64);
  };

  auto rdA = [&](int p, int m, int kk) -> bf16x8 {
    int r = wm * 128 + m * 16 + lr;
    return *(const bf16x8*)&lds[p * 32768 + r * 64 +
                                (((kk * 4 + lh) ^ (r & 7)) << 3)];
  };
  auto rdB = [&](int p, int n, int kk) -> bf16x8 {
    int r = wn * 64 + n * 16 + lr;
    return *(const bf16x8*)&lds[p * 32768 + 16384 + r * 64 +
                                (((kk * 4 + lh) ^ (r & 7)) << 3)];
  };

  auto tile4 = [&](int t, bool last) {
    const int p = t & 1;
    bf16x8 b[4][2], a0[2], a1[2];
#pragma unroll
    for (int q = 0; q < 4; ++q) {
      if (q == 0) {
#pragma unroll
        for (int n = 0; n < 4; ++n)
#pragma unroll
          for (int kk = 0; kk < 2; ++kk) b[n][kk] = rdB(p, n, kk);
      }
#pragma unroll
      for (int kk = 0; kk < 2; ++kk) {
        a0[kk] = rdA(p, 2 * q, kk);
        a1[kk] = rdA(p, 2 * q + 1, kk);
      }
      if (q == 0) {
        stageA3(t + 1);
      } else if (q == 1) {
        if (!last) stageB(t + 2, 0);
      } else if (q == 2) {
        if (!last) stageB(t + 2, 1);
      } else {
        if (!last) stageA012(t + 2);
        if (last)
          asm volatile("s_waitcnt vmcnt(0)" ::: "memory");
        else
          asm volatile("s_waitcnt vmcnt(7)" ::: "memory");
      }
      __builtin_amdgcn_s_barrier();
      asm volatile("s_waitcnt lgkmcnt(0)" ::: "memory");
      __builtin_amdgcn_sched_barrier(0);
      __builtin_amdgcn_s_setprio(1);
#pragma unroll
      for (int n = 0; n < 4; ++n)
#pragma unroll
        for (int kk = 0; kk < 2; ++kk) {
          acc[2 * q][n] = __builtin_amdgcn_mfma_f32_16x16x32_bf16(
              a0[kk], b[n][kk], acc[2 * q][n], 0, 0, 0);
          acc[2 * q + 1][n] = __builtin_amdgcn_mfma_f32_16x16x32_bf16(
              a1[kk], b[n][kk], acc[2 * q + 1][n], 0, 0, 0);
        }
      __builtin_amdgcn_s_setprio(0);
      __builtin_amdgcn_s_barrier();
      asm volatile("" ::: "memory");
    }
  };

  auto tileEpi = [&](int t) {
    const int p = t & 1;
    bf16x8 b[4][2], a0[2], a1[2];
#pragma unroll
    for (int n = 0; n < 4; ++n)
#pragma unroll
      for (int kk = 0; kk < 2; ++kk) b[n][kk] = rdB(p, n, kk);
#pragma unroll
    for (int q = 0; q < 4; ++q) {
#pragma unroll
      for (int kk = 0; kk < 2; ++kk) {
        a0[kk] = rdA(p, 2 * q, kk);
        a1[kk] = rdA(p, 2 * q + 1, kk);
      }
#pragma unroll
      for (int n = 0; n < 4; ++n)
#pragma unroll
        for (int kk = 0; kk < 2; ++kk) {
          acc[2 * q][n] = __builtin_amdgcn_mfma_f32_16x16x32_bf16(
              a0[kk], b[n][kk], acc[2 * q][n], 0, 0, 0);
          acc[2 * q + 1][n] = __builtin_amdgcn_mfma_f32_16x16x32_bf16(
              a1[kk], b[n][kk], acc[2 * q + 1][n], 0, 0, 0);
        }
    }
  };

  stageB(0, 0); stageB(0, 1); stageA012(0); stageA3(0);
  stageB(1, 0); stageB(1, 1); stageA012(1);
  asm volatile("s_waitcnt vmcnt(7)" ::: "memory");
  __builtin_amdgcn_s_barrier();

  for (int t = 0; t < 14; ++t) tile4(t, false);
  tile4(14, true);
  tileEpi(15);

#pragma unroll
  for (int m = 0; m < 8; ++m) {
    int gr0 = rowBase + wm * 128 + m * 16 + lh * 4;
    int b_ = gr0 >> 11, nx0 = gr0 & 2047;
#pragma unroll
    for (int n = 0; n < 4; ++n) {
      int gc = colBase + wn * 64 + n * 16 + lr;
      if (gc < 1024) {
        int hh = gc >> 6, d = gc & 63;
        size_t base = (((size_t)b_ * NH + hh) * NX + nx0) * DH + d;
#pragma unroll
        for (int j = 0; j < 4; ++j)
          outK[base + (size_t)j * DH] = f2bf(acc[m][n][j]);
      } else {
        int c2 = gc - 1024;
        int hh = c2 >> 6, d = c2 & 63;
        ushort4 pv;
        pv.x = f2bf(acc[m][n][0]);
        pv.y = f2bf(acc[m][n][1]);
        pv.z = f2bf(acc[m][n][2]);
        pv.w = f2bf(acc[m][n][3]);
        *(ushort4*)&outV[(((size_t)b_ * NH + hh) * DH + d) * NX + nx0] = pv;
      }
    }
  }
}

// ---------------- gemm_proj: 64x128 tiles, 256 blocks (full CU fill) ----------------

__global__ __launch_bounds__(256) void gemm_proj(
    const uint16_t* __restrict__ A, const uint16_t* __restrict__ BT,
    float* __restrict__ outF, const float* __restrict__ bias) {
  constexpr int K = 1024;
  __shared__ __align__(16) uint16_t sA[64 * 32];
  __shared__ __align__(16) uint16_t sB[128 * 32];

  const int tid = threadIdx.x;
  const int wv = tid >> 6;
  const int lane = tid & 63;
  const int lr = lane & 15;
  const int lh = lane >> 4;
  const int wm = wv >> 1, wn = wv & 1;
  const int rowBase = blockIdx.x * 64;
  const int colBase = blockIdx.y * 128;

  f32x4 zero4 = {0.f, 0.f, 0.f, 0.f};
  f32x4 acc[2][4];
#pragma unroll
  for (int m = 0; m < 2; ++m)
#pragma unroll
    for (int n = 0; n < 4; ++n) acc[m][n] = zero4;

  for (int k0 = 0; k0 < K; k0 += 32) {
    {
      int row = tid >> 2, cc = tid & 3;
      int sc = cc ^ ((row >> 1) & 3);
      GLD16(A + (size_t)(rowBase + row) * K + k0 + sc * 8,
            sA + ((size_t)wv * 64) * 8);
    }
#pragma unroll
    for (int it = 0; it < 2; ++it) {
      int s = it * 256 + tid;
      int row = s >> 2, cc = s & 3;
      int sc = cc ^ ((row >> 1) & 3);
      GLD16(BT + (size_t)(colBase + row) * K + k0 + sc * 8,
            sB + ((size_t)it * 256 + wv * 64) * 8);
    }
    __syncthreads();
    bf16x8 af[2], bfr[4];
#pragma unroll
    for (int m = 0; m < 2; ++m) {
      int r = wm * 32 + m * 16 + lr;
      af[m] = *(const bf16x8*)&sA[r * 32 + ((lh ^ ((r >> 1) & 3)) << 3)];
    }
#pragma unroll
    for (int n = 0; n < 4; ++n) {
      int r = wn * 64 + n * 16 + lr;
      bfr[n] = *(const bf16x8*)&sB[r * 32 + ((lh ^ ((r >> 1) & 3)) << 3)];
    }
#pragma unroll
    for (int m = 0; m < 2; ++m)
#pragma unroll
      for (int n = 0; n < 4; ++n)
        acc[m][n] = __builtin_amdgcn_mfma_f32_16x16x32_bf16(af[m], bfr[n],
                                                            acc[m][n], 0, 0, 0);
    __syncthreads();
  }

#pragma unroll
  for (int m = 0; m < 2; ++m) {
    int gr0 = rowBase + wm * 32 + m * 16 + lh * 4;
#pragma unroll
    for (int n = 0; n < 4; ++n) {
      int gc = colBase + wn * 64 + n * 16 + lr;
      float bi = bias[gc];
#pragma unroll
      for (int j = 0; j < 4; ++j)
        outF[(size_t)(gr0 + j) * 1024 + gc] = acc[m][n][j] + bi;
    }
  }
}

// ---------------- gatev: gate reduce (blocks 0..63) + vcolsum (blocks 64..319) ----------------

__global__ __launch_bounds__(256) void gatev_kernel(
    const float* __restrict__ gv, float* __restrict__ gate,
    const uint16_t* __restrict__ VT, float* __restrict__ vcs) {
  const int tid = threadIdx.x;
  const int wv = tid >> 6, lane = tid & 63;
  if (blockIdx.x < 64) {
    const int bh = blockIdx.x;
    const float* p = gv + (size_t)bh * NX;
    float s = 0.f, mx = -1e30f;
    for (int i = tid; i < NX; i += 256) {
      float v = p[i];
      s += v;
      mx = fmaxf(mx, v);
    }
#pragma unroll
    for (int off = 1; off < 64; off <<= 1) {
      s += __shfl_xor(s, off, 64);
      mx = fmaxf(mx, __shfl_xor(mx, off, 64));
    }
    __shared__ float ss[4], sm[4];
    if (lane == 0) { ss[wv] = s; sm[wv] = mx; }
    __syncthreads();
    if (tid == 0) {
      float S = ss[0] + ss[1] + ss[2] + ss[3];
      float M = fmaxf(fmaxf(sm[0], sm[1]), fmaxf(sm[2], sm[3]));
      gate[bh] = 0.5f * (S / (float)NX) + 0.5f * M;
    }
  } else {
    const int idx = blockIdx.x - 64;  // 0..255
    const int bh = idx & 63, quarter = idx >> 6;
#pragma unroll
    for (int dd = 0; dd < 4; ++dd) {
      int d = quarter * 16 + dd * 4 + wv;
      const uint16_t* row = VT + ((size_t)bh * DH + d) * NX;
      float s = 0.f;
#pragma unroll
      for (int i = 0; i < 4; ++i) {
        bf16x8 v = *(const bf16x8*)&row[(i * 64 + lane) * 8];
#pragma unroll
        for (int j = 0; j < 8; ++j) s += (float)v[j];
      }
#pragma unroll
      for (int off = 1; off < 64; off <<= 1) s += __shfl_xor(s, off, 64);
      if (lane == 0) vcs[bh * DH + d] = s;
    }
  }
}

// ---------------- attention: round-15 proven (dbuf K/V, no mid barrier, setprio) ----------------

__global__ __launch_bounds__(256) void attn_kernel(
    const uint16_t* __restrict__ Q, const uint16_t* __restrict__ K,
    const uint16_t* __restrict__ VT, const float* __restrict__ gate,
    const float* __restrict__ attw, const float* __restrict__ vcs,
    uint16_t* __restrict__ ctxh) {
  __shared__ __align__(16) uint16_t sK[2][128 * 64];
  __shared__ __align__(16) uint16_t sV[2][64 * 128];
  __shared__ __align__(16) __bf16 sPe[64 * 128];

  const int tid = threadIdx.x;
  const int wv = tid >> 6;
  const int lane = tid & 63;
  const int lr = lane & 15;
  const int lh = lane >> 4;
  const int bh = blockIdx.x;
  const int q0 = blockIdx.y * 64;
  const float g = gate[bh];
  const float w = attw[0];

  const uint16_t* Qb = Q + ((size_t)bh * NQ + q0) * DH;
  const uint16_t* Kb = K + (size_t)bh * NX * DH;
  const uint16_t* Vb = VT + (size_t)bh * DH * NX;

  auto stageKV = [&](int kt, int p) {  // 8 loads/thread
#pragma unroll
    for (int it = 0; it < 4; ++it) {
      int s = it * 256 + tid;
      int row = s >> 3, cc = s & 7;
      int sc = cc ^ (row & 7);
      GLD16(Kb + (size_t)(kt * 128 + row) * DH + sc * 8,
            sK[p] + ((size_t)it * 256 + wv * 64) * 8);
    }
#pragma unroll
    for (int it = 0; it < 4; ++it) {
      int s = it * 256 + tid;
      int row = s >> 4, cc = s & 15;
      int sc = cc ^ (row & 15);
      GLD16(Vb + (size_t)row * NX + kt * 128 + sc * 8,
            sV[p] + ((size_t)it * 256 + wv * 64) * 8);
    }
  };

  bf16x8 qa[2];
#pragma unroll
  for (int kk = 0; kk < 2; ++kk)
    qa[kk] = *(const bf16x8*)&Qb[(wv * 16 + lr) * DH + kk * 32 + lh * 8];

  float lp[4] = {0.f, 0.f, 0.f, 0.f};
  f32x4 zero4 = {0.f, 0.f, 0.f, 0.f};
  f32x4 accp[4];
#pragma unroll
  for (int d = 0; d < 4; ++d) accp[d] = zero4;

  stageKV(0, 0);  // prologue

  for (int kt = 0; kt < 16; ++kt) {
    const int p = kt & 1;
    if (kt < 15) {
      stageKV(kt + 1, p ^ 1);
      asm volatile("s_waitcnt vmcnt(8)" ::: "memory");
    } else {
      asm volatile("s_waitcnt vmcnt(0)" ::: "memory");
    }
    __builtin_amdgcn_s_barrier();  // tile kt's K/V visible to all waves
    __builtin_amdgcn_s_setprio(1);
#pragma unroll
    for (int n = 0; n < 8; ++n) {
      f32x4 a4 = {0.f, 0.f, 0.f, 0.f};
      int r = n * 16 + lr;
#pragma unroll
      for (int kk = 0; kk < 2; ++kk) {
        bf16x8 kb =
            *(const bf16x8*)&sK[p][r * 64 + (((kk * 4 + lh) ^ (r & 7)) << 3)];
        a4 = __builtin_amdgcn_mfma_f32_16x16x32_bf16(qa[kk], kb, a4, 0, 0, 0);
      }
      __builtin_amdgcn_s_setprio(0);
#pragma unroll
      for (int j = 0; j < 4; ++j) {
        float e = __expf(a4[j]);
        lp[j] += e;
        int qr = wv * 16 + lh * 4 + j;
        int key = n * 16 + lr;
        int idx = qr * 128 + ((((key >> 3) ^ (qr & 15))) << 3) + (key & 7);
        sPe[idx] = (__bf16)e;
      }
      __builtin_amdgcn_s_setprio(1);
    }
    __builtin_amdgcn_s_setprio(0);
    // sPe is wave-private: wave-local ordering only (no block barrier).
    asm volatile("s_waitcnt lgkmcnt(0)" ::: "memory");
    __builtin_amdgcn_sched_barrier(0);
    const int prow = wv * 16 + lr;
    __builtin_amdgcn_s_setprio(1);
#pragma unroll
    for (int kk = 0; kk < 4; ++kk) {
      int pidx = prow * 128 + (((kk * 4 + lh) ^ (prow & 15)) << 3);
      bf16x8 pe = *(const bf16x8*)&sPe[pidx];
#pragma unroll
      for (int df = 0; df < 4; ++df) {
        int vr = df * 16 + lr;
        bf16x8 vb =
            *(const bf16x8*)&sV[p][vr * 128 + (((kk * 4 + lh) ^ (vr & 15)) << 3)];
        accp[df] = __builtin_amdgcn_mfma_f32_16x16x32_bf16(pe, vb, accp[df], 0, 0, 0);
      }
    }
    __builtin_amdgcn_s_setprio(0);
    asm volatile("s_waitcnt lgkmcnt(0)" ::: "memory");
    __builtin_amdgcn_s_barrier();  // all waves done reading buf p before restage
  }
#pragma unroll
  for (int off = 1; off < 16; off <<= 1)
#pragma unroll
    for (int j = 0; j < 4; ++j) lp[j] += __shfl_xor(lp[j], off, 64);

  const int b = bh >> 4, h = bh & 15;
  const float c1 = w / ((float)NX + g);
  const float c2 = w * g / ((float)NX + g) + (1.f - w);
  float rl[4];
#pragma unroll
  for (int j = 0; j < 4; ++j) rl[j] = 1.f / lp[j];
#pragma unroll
  for (int df = 0; df < 4; ++df) {
    int d = df * 16 + lr;
    float cv = vcs[bh * DH + d];
#pragma unroll
    for (int j = 0; j < 4; ++j) {
      int qr = q0 + wv * 16 + lh * 4 + j;
      float p = accp[df][j] * rl[j];
      ctxh[(((size_t)b * NQ + qr) * NH + h) * DH + d] = f2bf(c1 * cv + c2 * p);
    }
  }
}

// ---------------- launch ----------------

extern "C" void kernel_launch(void* const* d_in, const int* in_sizes, int n_in,
                              void* d_out, int out_size, void* d_ws,
                              size_t ws_size, hipStream_t stream) {
  const float* x = (const float*)d_in[0];
  const float* cls = (const float*)d_in[1];
  const float* w_kv = (const float*)d_in[2];
  const float* w_q = (const float*)d_in[3];
  const float* w_la = (const float*)d_in[4];
  const float* w_proj = (const float*)d_in[5];
  const float* b_proj = (const float*)d_in[6];
  const float* att_w = (const float*)d_in[7];
  float* out = (float*)d_out;

  char* ws = (char*)d_ws;
  size_t off = 0;
  auto alloc = [&](size_t bytes) {
    void* p = ws + off;
    off += (bytes + 255) & ~(size_t)255;
    return p;
  };
  uint16_t* xh = (uint16_t*)alloc(4ull * NX * CDIM * 2);
  uint16_t* ch = (uint16_t*)alloc(4ull * NQ * CDIM * 2);
  uint16_t* wkvT = (uint16_t*)alloc(2048ull * 1024 * 2);
  uint16_t* wqT = (uint16_t*)alloc(1024ull * 1024 * 2);
  uint16_t* wpT = (uint16_t*)alloc(1024ull * 1024 * 2);
  uint16_t* kbf = (uint16_t*)alloc(4ull * NH * NX * DH * 2);
  uint16_t* vT = (uint16_t*)alloc(4ull * NH * DH * NX * 2);
  uint16_t* qbf = (uint16_t*)alloc(4ull * NH * NQ * DH * 2);
  float* gv = (float*)alloc(4ull * NH * NX * 4);
  float* gate = (float*)alloc(1024);
  float* vcs = (float*)alloc(4ull * NH * DH * 4);
  uint16_t* ctxh = (uint16_t*)alloc(4ull * NQ * CDIM * 2);

  prep_kernel<<<3584, 256, 0, stream>>>(x, xh, cls, ch, w_kv, wkvT, w_q, wqT,
                                        w_proj, wpT);

  aux_mm_kernel<<<384, 256, 0, stream>>>(ch, wqT, qbf, xh, w_la, gv);
  gemm_kv8<<<dim3(32, 8), 512, 0, stream>>>(xh, wkvT, kbf, vT);

  gatev_kernel<<<320, 256, 0, stream>>>(gv, gate, vT, vcs);

  attn_kernel<<<dim3(64, 8), 256, 0, stream>>>(qbf, kbf, vT, gate, att_w, vcs, ctxh);

  gemm_proj<<<dim3(32, 8), 256, 0, stream>>>(ctxh, wpT, out, b_proj);
}

// Round 17
// 131.447 us; speedup vs baseline: 1.1547x; 1.0032x over previous
//
#include <hip/hip_runtime.h>
#include <stdint.h>

#define NX 2048
#define NQ 512
#define CDIM 1024
#define NH 16
#define DH 64

typedef __attribute__((ext_vector_type(8))) __bf16 bf16x8;
typedef __attribute__((ext_vector_type(4))) float f32x4;

__device__ __forceinline__ uint16_t f2bf(float f) {
  uint32_t i = __float_as_uint(f);
  uint32_t r = i + 0x7fffu + ((i >> 16) & 1u);
  return (uint16_t)(r >> 16);
}

// 2^x in one v_exp_f32 (ISA: v_exp_f32 D=2^S0). Non-volatile: scheduler-free.
__device__ __forceinline__ float exp2_fast(float x) {
  float r;
  asm("v_exp_f32 %0, %1" : "=v"(r) : "v"(x));
  return r;
}

#define GLD16(g, l)                                                            \
  __builtin_amdgcn_global_load_lds(                                            \
      (const __attribute__((address_space(1))) uint32_t*)(g),                  \
      (__attribute__((address_space(3))) uint32_t*)(l), 16, 0, 0)

// ---------------- prep: casts (x,cls) + weight transposes, one launch ----------------

__global__ __launch_bounds__(256) void prep_kernel(
    const float* __restrict__ x, uint16_t* __restrict__ xh,
    const float* __restrict__ cls, uint16_t* __restrict__ ch,
    const float* __restrict__ w_kv, uint16_t* __restrict__ wkvT,
    const float* __restrict__ w_q, uint16_t* __restrict__ wqT,
    const float* __restrict__ w_proj, uint16_t* __restrict__ wpT) {
  __shared__ uint16_t tile[64][65];
  const int tid = threadIdx.x;
  const int bid = blockIdx.x;
  if (bid < 2048) {
    const int n40 = 4 * NX * CDIM / 4, n41 = 4 * NQ * CDIM / 4;
    const int ntot = n40 + n41;
    const int stride = 2048 * 256;
    for (int i = bid * 256 + tid; i < ntot; i += stride) {
      if (i < n40) {
        float4 v = ((const float4*)x)[i];
        ushort4 o;
        o.x = f2bf(v.x); o.y = f2bf(v.y); o.z = f2bf(v.z); o.w = f2bf(v.w);
        ((ushort4*)xh)[i] = o;
      } else {
        float4 v = ((const float4*)cls)[i - n40];
        ushort4 o;
        o.x = f2bf(v.x); o.y = f2bf(v.y); o.z = f2bf(v.z); o.w = f2bf(v.w);
        ((ushort4*)ch)[i - n40] = o;
      }
    }
  } else {
    const int rem = bid - 2048;          // 0..1535
    const int z = rem >> 9;              // 0..2
    const int bx = rem & 31, by = (rem >> 5) & 15;
    const float* src;
    uint16_t* dst;
    int N;
    if (z == 0) { src = w_kv; dst = wkvT; N = 2048; }
    else if (z == 1) { src = w_q; dst = wqT; N = 1024; }
    else { src = w_proj; dst = wpT; N = 1024; }
    const int n0 = bx * 64;
    if (n0 >= N) return;
    const int k0 = by * 64;
#pragma unroll
    for (int it = 0; it < 16; ++it) {
      int idx = it * 256 + tid;
      int r = idx >> 6, c = idx & 63;
      tile[r][c] = f2bf(src[(size_t)(k0 + r) * N + n0 + c]);
    }
    __syncthreads();
#pragma unroll
    for (int it = 0; it < 16; ++it) {
      int idx = it * 256 + tid;
      int r = idx >> 6, c = idx & 63;
      dst[(size_t)(n0 + r) * 1024 + k0 + c] = tile[c][r];
    }
  }
}

// ---------------- aux_mm: q-proj 64x128 tiles (blocks 0..255) + gate GEMV tail ----------------
// q pre-scale now 0.125*log2(e): scores come out of QK^T already in log2
// units so attn uses a bare v_exp_f32 (2^x) — exact same math, one fewer
// dependent v_mul per exp.

__global__ __launch_bounds__(256) void aux_mm_kernel(
    const uint16_t* __restrict__ ch, const uint16_t* __restrict__ wqT,
    uint16_t* __restrict__ qbf, const uint16_t* __restrict__ xh,
    const float* __restrict__ wla, float* __restrict__ gv) {
  __shared__ __align__(16) uint16_t smem[16 * 1024];  // 32 KB union
  const int tid = threadIdx.x;
  const int wv = tid >> 6;
  const int lane = tid & 63;
  const int lr = lane & 15;
  const int lh = lane >> 4;

  if (blockIdx.x < 256) {
    uint16_t* sA = smem;              // 64*32
    uint16_t* sB = smem + 64 * 32;    // 128*32
    const int wm = wv >> 1, wn = wv & 1;
    const int rowBase = (blockIdx.x & 31) * 64;
    const int colBase = (blockIdx.x >> 5) * 128;

    f32x4 zero4 = {0.f, 0.f, 0.f, 0.f};
    f32x4 acc[2][4];
#pragma unroll
    for (int m = 0; m < 2; ++m)
#pragma unroll
      for (int n = 0; n < 4; ++n) acc[m][n] = zero4;

    for (int k0 = 0; k0 < 1024; k0 += 32) {
      {
        int row = tid >> 2, cc = tid & 3;
        int sc = cc ^ ((row >> 1) & 3);
        GLD16(ch + (size_t)(rowBase + row) * 1024 + k0 + sc * 8,
              sA + ((size_t)wv * 64) * 8);
      }
#pragma unroll
      for (int it = 0; it < 2; ++it) {
        int s = it * 256 + tid;
        int row = s >> 2, cc = s & 3;
        int sc = cc ^ ((row >> 1) & 3);
        GLD16(wqT + (size_t)(colBase + row) * 1024 + k0 + sc * 8,
              sB + ((size_t)it * 256 + wv * 64) * 8);
      }
      __syncthreads();
      bf16x8 af[2], bfr[4];
#pragma unroll
      for (int m = 0; m < 2; ++m) {
        int r = wm * 32 + m * 16 + lr;
        af[m] = *(const bf16x8*)&sA[r * 32 + ((lh ^ ((r >> 1) & 3)) << 3)];
      }
#pragma unroll
      for (int n = 0; n < 4; ++n) {
        int r = wn * 64 + n * 16 + lr;
        bfr[n] = *(const bf16x8*)&sB[r * 32 + ((lh ^ ((r >> 1) & 3)) << 3)];
      }
#pragma unroll
      for (int m = 0; m < 2; ++m)
#pragma unroll
        for (int n = 0; n < 4; ++n)
          acc[m][n] = __builtin_amdgcn_mfma_f32_16x16x32_bf16(af[m], bfr[n],
                                                              acc[m][n], 0, 0, 0);
      __syncthreads();
    }

    const float qs = 0.125f * 1.44269504088896340736f;  // /8 * log2(e)
#pragma unroll
    for (int m = 0; m < 2; ++m) {
      int gr0 = rowBase + wm * 32 + m * 16 + lh * 4;
      int b = gr0 >> 9, nq0 = gr0 & 511;
#pragma unroll
      for (int n = 0; n < 4; ++n) {
        int gc = colBase + wn * 64 + n * 16 + lr;
        int hh = gc >> 6, d = gc & 63;
        size_t base = (((size_t)b * NH + hh) * NQ + nq0) * DH + d;
#pragma unroll
        for (int j = 0; j < 4; ++j)
          qbf[base + (size_t)j * DH] = f2bf(acc[m][n][j] * qs);
      }
    }
  } else {
    uint16_t* sW = smem;
#pragma unroll
    for (int it = 0; it < 64; ++it) {
      int i = it * 256 + tid;
      int c = i >> 4, h = i & 15;
      sW[h * 1024 + (((c >> 3) ^ (h & 7)) << 3) + (c & 7)] = f2bf(wla[i]);
    }
    __syncthreads();

    const int rb = (blockIdx.x - 256) * 64 + wv * 16;
    f32x4 acc = {0.f, 0.f, 0.f, 0.f};
    for (int t = 0; t < 32; ++t) {
      bf16x8 af = *(const bf16x8*)&xh[(size_t)(rb + lr) * 1024 + t * 32 + lh * 8];
      bf16x8 bf = *(const bf16x8*)&sW[lr * 1024 + (((t * 4 + lh) ^ (lr & 7)) << 3)];
      acc = __builtin_amdgcn_mfma_f32_16x16x32_bf16(af, bf, acc, 0, 0, 0);
    }
    int nxg = rb + lh * 4;
    int b = nxg >> 11, nx = nxg & 2047;
    float4 st = {acc[0], acc[1], acc[2], acc[3]};
    *(float4*)&gv[((size_t)b * NH + lr) * NX + nx] = st;
  }
}

// ---------------- 8-phase 256x256 GEMM for x@w_kv (round-8 proven, 256 blocks = 1/CU) ----------------

__global__ __launch_bounds__(512, 2) void gemm_kv8(
    const uint16_t* __restrict__ A, const uint16_t* __restrict__ BT,
    uint16_t* __restrict__ outK, uint16_t* __restrict__ outV) {
  __shared__ __align__(16) uint16_t lds[65536];  // [buf][A|B][256][64]

  const int tid = threadIdx.x;
  const int wid = tid >> 6;
  const int lane = tid & 63;
  const int lr = lane & 15;
  const int lh = lane >> 4;
  const int wm = wid >> 2;
  const int wn = wid & 3;
  const int rowBase = blockIdx.x * 256;
  const int colBase = blockIdx.y * 256;

  f32x4 acc[8][4];
#pragma unroll
  for (int m = 0; m < 8; ++m)
#pragma unroll
    for (int n = 0; n < 4; ++n) acc[m][n] = (f32x4){0.f, 0.f, 0.f, 0.f};

  auto stageB = [&](int T, int h) {
    const uint16_t* srcp = BT + (size_t)(colBase + h * 128) * 1024 + T * 64;
    uint16_t* dst = lds + ((T & 1) * 32768 + 16384 + h * 8192);
#pragma unroll
    for (int it = 0; it < 2; ++it) {
      int s = it * 512 + tid;
      int row = s >> 3, cc = s & 7;
      int sc = cc ^ (row & 7);
      GLD16(srcp + (size_t)row * 1024 + sc * 8,
            dst + ((size_t)it * 512 + wid * 64) * 8);
    }
  };
  auto stageA012 = [&](int T) {
    const uint16_t* srcp = A + (size_t)rowBase * 1024 + T * 64;
    uint16_t* dstbase = lds + (T & 1) * 32768;
    int r64 = tid >> 3, cc = tid & 7;
#pragma unroll
    for (int st = 0; st < 3; ++st) {
      int rloc = (r64 < 32) ? (st * 32 + r64) : (96 + st * 32 + r64);
      int sc = cc ^ (rloc & 7);
      int wrow = (wid < 4) ? (st * 32 + wid * 8) : (128 + st * 32 + (wid - 4) * 8);
      GLD16(srcp + (size_t)rloc * 1024 + sc * 8, dstbase + (size_t)wrow * 64);
    }
  };
  auto stageA3 = [&](int T) {
    const uint16_t* srcp = A + (size_t)rowBase * 1024 + T * 64;
    uint16_t* dstbase = lds + (T & 1) * 32768;
    int r64 = tid >> 3, cc = tid & 7;
    int rloc = (r64 < 32) ? (96 + r64) : (192 + r64);
    int sc = cc ^ (rloc & 7);
    int wrow = (wid < 4) ? (96 + wid * 8) : (224 + (wid - 4) * 8);
    GLD16(srcp + (size_t)rloc * 1024 + sc * 8, dstbase + (size_t)wrow * 64);
  };

  auto rdA = [&](int p, int m, int kk) -> bf16x8 {
    int r = wm * 128 + m * 16 + lr;
    return *(const bf16x8*)&lds[p * 32768 + r * 64 +
                                (((kk * 4 + lh) ^ (r & 7)) << 3)];
  };
  auto rdB = [&](int p, int n, int kk) -> bf16x8 {
    int r = wn * 64 + n * 16 + lr;
    return *(const bf16x8*)&lds[p * 32768 + 16384 + r * 64 +
                                (((kk * 4 + lh) ^ (r & 7)) << 3)];
  };

  auto tile4 = [&](int t, bool last) {
    const int p = t & 1;
    bf16x8 b[4][2], a0[2], a1[2];
#pragma unroll
    for (int q = 0; q < 4; ++q) {
      if (q == 0) {
#pragma unroll
        for (int n = 0; n < 4; ++n)
#pragma unroll
          for (int kk = 0; kk < 2; ++kk) b[n][kk] = rdB(p, n, kk);
      }
#pragma unroll
      for (int kk = 0; kk < 2; ++kk) {
        a0[kk] = rdA(p, 2 * q, kk);
        a1[kk] = rdA(p, 2 * q + 1, kk);
      }
      if (q == 0) {
        stageA3(t + 1);
      } else if (q == 1) {
        if (!last) stageB(t + 2, 0);
      } else if (q == 2) {
        if (!last) stageB(t + 2, 1);
      } else {
        if (!last) stageA012(t + 2);
        if (last)
          asm volatile("s_waitcnt vmcnt(0)" ::: "memory");
        else
          asm volatile("s_waitcnt vmcnt(7)" ::: "memory");
      }
      __builtin_amdgcn_s_barrier();
      asm volatile("s_waitcnt lgkmcnt(0)" ::: "memory");
      __builtin_amdgcn_sched_barrier(0);
      __builtin_amdgcn_s_setprio(1);
#pragma unroll
      for (int n = 0; n < 4; ++n)
#pragma unroll
        for (int kk = 0; kk < 2; ++kk) {
          acc[2 * q][n] = __builtin_amdgcn_mfma_f32_16x16x32_bf16(
              a0[kk], b[n][kk], acc[2 * q][n], 0, 0, 0);
          acc[2 * q + 1][n] = __builtin_amdgcn_mfma_f32_16x16x32_bf16(
              a1[kk], b[n][kk], acc[2 * q + 1][n], 0, 0, 0);
        }
      __builtin_amdgcn_s_setprio(0);
      __builtin_amdgcn_s_barrier();
      asm volatile("" ::: "memory");
    }
  };

  auto tileEpi = [&](int t) {
    const int p = t & 1;
    bf16x8 b[4][2], a0[2], a1[2];
#pragma unroll
    for (int n = 0; n < 4; ++n)
#pragma unroll
      for (int kk = 0; kk < 2; ++kk) b[n][kk] = rdB(p, n, kk);
#pragma unroll
    for (int q = 0; q < 4; ++q) {
#pragma unroll
      for (int kk = 0; kk < 2; ++kk) {
        a0[kk] = rdA(p, 2 * q, kk);
        a1[kk] = rdA(p, 2 * q + 1, kk);
      }
#pragma unroll
      for (int n = 0; n < 4; ++n)
#pragma unroll
        for (int kk = 0; kk < 2; ++kk) {
          acc[2 * q][n] = __builtin_amdgcn_mfma_f32_16x16x32_bf16(
              a0[kk], b[n][kk], acc[2 * q][n], 0, 0, 0);
          acc[2 * q + 1][n] = __builtin_amdgcn_mfma_f32_16x16x32_bf16(
              a1[kk], b[n][kk], acc[2 * q + 1][n], 0, 0, 0);
        }
    }
  };

  stageB(0, 0); stageB(0, 1); stageA012(0); stageA3(0);
  stageB(1, 0); stageB(1, 1); stageA012(1);
  asm volatile("s_waitcnt vmcnt(7)" ::: "memory");
  __builtin_amdgcn_s_barrier();

  for (int t = 0; t < 14; ++t) tile4(t, false);
  tile4(14, true);
  tileEpi(15);

#pragma unroll
  for (int m = 0; m < 8; ++m) {
    int gr0 = rowBase + wm * 128 + m * 16 + lh * 4;
    int b_ = gr0 >> 11, nx0 = gr0 & 2047;
#pragma unroll
    for (int n = 0; n < 4; ++n) {
      int gc = colBase + wn * 64 + n * 16 + lr;
      if (gc < 1024) {
        int hh = gc >> 6, d = gc & 63;
        size_t base = (((size_t)b_ * NH + hh) * NX + nx0) * DH + d;
#pragma unroll
        for (int j = 0; j < 4; ++j)
          outK[base + (size_t)j * DH] = f2bf(acc[m][n][j]);
      } else {
        int c2 = gc - 1024;
        int hh = c2 >> 6, d = c2 & 63;
        ushort4 pv;
        pv.x = f2bf(acc[m][n][0]);
        pv.y = f2bf(acc[m][n][1]);
        pv.z = f2bf(acc[m][n][2]);
        pv.w = f2bf(acc[m][n][3]);
        *(ushort4*)&outV[(((size_t)b_ * NH + hh) * DH + d) * NX + nx0] = pv;
      }
    }
  }
}

// ---------------- gemm_proj: 64x128 tiles, 256 blocks (full CU fill) ----------------

__global__ __launch_bounds__(256) void gemm_proj(
    const uint16_t* __restrict__ A, const uint16_t* __restrict__ BT,
    float* __restrict__ outF, const float* __restrict__ bias) {
  constexpr int K = 1024;
  __shared__ __align__(16) uint16_t sA[64 * 32];
  __shared__ __align__(16) uint16_t sB[128 * 32];

  const int tid = threadIdx.x;
  const int wv = tid >> 6;
  const int lane = tid & 63;
  const int lr = lane & 15;
  const int lh = lane >> 4;
  const int wm = wv >> 1, wn = wv & 1;
  const int rowBase = blockIdx.x * 64;
  const int colBase = blockIdx.y * 128;

  f32x4 zero4 = {0.f, 0.f, 0.f, 0.f};
  f32x4 acc[2][4];
#pragma unroll
  for (int m = 0; m < 2; ++m)
#pragma unroll
    for (int n = 0; n < 4; ++n) acc[m][n] = zero4;

  for (int k0 = 0; k0 < K; k0 += 32) {
    {
      int row = tid >> 2, cc = tid & 3;
      int sc = cc ^ ((row >> 1) & 3);
      GLD16(A + (size_t)(rowBase + row) * K + k0 + sc * 8,
            sA + ((size_t)wv * 64) * 8);
    }
#pragma unroll
    for (int it = 0; it < 2; ++it) {
      int s = it * 256 + tid;
      int row = s >> 2, cc = s & 3;
      int sc = cc ^ ((row >> 1) & 3);
      GLD16(BT + (size_t)(colBase + row) * K + k0 + sc * 8,
            sB + ((size_t)it * 256 + wv * 64) * 8);
    }
    __syncthreads();
    bf16x8 af[2], bfr[4];
#pragma unroll
    for (int m = 0; m < 2; ++m) {
      int r = wm * 32 + m * 16 + lr;
      af[m] = *(const bf16x8*)&sA[r * 32 + ((lh ^ ((r >> 1) & 3)) << 3)];
    }
#pragma unroll
    for (int n = 0; n < 4; ++n) {
      int r = wn * 64 + n * 16 + lr;
      bfr[n] = *(const bf16x8*)&sB[r * 32 + ((lh ^ ((r >> 1) & 3)) << 3)];
    }
#pragma unroll
    for (int m = 0; m < 2; ++m)
#pragma unroll
      for (int n = 0; n < 4; ++n)
        acc[m][n] = __builtin_amdgcn_mfma_f32_16x16x32_bf16(af[m], bfr[n],
                                                            acc[m][n], 0, 0, 0);
    __syncthreads();
  }

#pragma unroll
  for (int m = 0; m < 2; ++m) {
    int gr0 = rowBase + wm * 32 + m * 16 + lh * 4;
#pragma unroll
    for (int n = 0; n < 4; ++n) {
      int gc = colBase + wn * 64 + n * 16 + lr;
      float bi = bias[gc];
#pragma unroll
      for (int j = 0; j < 4; ++j)
        outF[(size_t)(gr0 + j) * 1024 + gc] = acc[m][n][j] + bi;
    }
  }
}

// ---------------- gatev: gate reduce (blocks 0..63) + vcolsum (blocks 64..319) ----------------

__global__ __launch_bounds__(256) void gatev_kernel(
    const float* __restrict__ gv, float* __restrict__ gate,
    const uint16_t* __restrict__ VT, float* __restrict__ vcs) {
  const int tid = threadIdx.x;
  const int wv = tid >> 6, lane = tid & 63;
  if (blockIdx.x < 64) {
    const int bh = blockIdx.x;
    const float* p = gv + (size_t)bh * NX;
    float s = 0.f, mx = -1e30f;
    for (int i = tid; i < NX; i += 256) {
      float v = p[i];
      s += v;
      mx = fmaxf(mx, v);
    }
#pragma unroll
    for (int off = 1; off < 64; off <<= 1) {
      s += __shfl_xor(s, off, 64);
      mx = fmaxf(mx, __shfl_xor(mx, off, 64));
    }
    __shared__ float ss[4], sm[4];
    if (lane == 0) { ss[wv] = s; sm[wv] = mx; }
    __syncthreads();
    if (tid == 0) {
      float S = ss[0] + ss[1] + ss[2] + ss[3];
      float M = fmaxf(fmaxf(sm[0], sm[1]), fmaxf(sm[2], sm[3]));
      gate[bh] = 0.5f * (S / (float)NX) + 0.5f * M;
    }
  } else {
    const int idx = blockIdx.x - 64;  // 0..255
    const int bh = idx & 63, quarter = idx >> 6;
#pragma unroll
    for (int dd = 0; dd < 4; ++dd) {
      int d = quarter * 16 + dd * 4 + wv;
      const uint16_t* row = VT + ((size_t)bh * DH + d) * NX;
      float s = 0.f;
#pragma unroll
      for (int i = 0; i < 4; ++i) {
        bf16x8 v = *(const bf16x8*)&row[(i * 64 + lane) * 8];
#pragma unroll
        for (int j = 0; j < 8; ++j) s += (float)v[j];
      }
#pragma unroll
      for (int off = 1; off < 64; off <<= 1) s += __shfl_xor(s, off, 64);
      if (lane == 0) vcs[bh * DH + d] = s;
    }
  }
}

// ---------------- attention: round-15 structure; scores in log2 units -> bare v_exp_f32 ----------------

__global__ __launch_bounds__(256) void attn_kernel(
    const uint16_t* __restrict__ Q, const uint16_t* __restrict__ K,
    const uint16_t* __restrict__ VT, const float* __restrict__ gate,
    const float* __restrict__ attw, const float* __restrict__ vcs,
    uint16_t* __restrict__ ctxh) {
  __shared__ __align__(16) uint16_t sK[2][128 * 64];
  __shared__ __align__(16) uint16_t sV[2][64 * 128];
  __shared__ __align__(16) __bf16 sPe[64 * 128];

  const int tid = threadIdx.x;
  const int wv = tid >> 6;
  const int lane = tid & 63;
  const int lr = lane & 15;
  const int lh = lane >> 4;
  const int bh = blockIdx.x;
  const int q0 = blockIdx.y * 64;
  const float g = gate[bh];
  const float w = attw[0];

  const uint16_t* Qb = Q + ((size_t)bh * NQ + q0) * DH;
  const uint16_t* Kb = K + (size_t)bh * NX * DH;
  const uint16_t* Vb = VT + (size_t)bh * DH * NX;

  auto stageKV = [&](int kt, int p) {  // 8 loads/thread
#pragma unroll
    for (int it = 0; it < 4; ++it) {
      int s = it * 256 + tid;
      int row = s >> 3, cc = s & 7;
      int sc = cc ^ (row & 7);
      GLD16(Kb + (size_t)(kt * 128 + row) * DH + sc * 8,
            sK[p] + ((size_t)it * 256 + wv * 64) * 8);
    }
#pragma unroll
    for (int it = 0; it < 4; ++it) {
      int s = it * 256 + tid;
      int row = s >> 4, cc = s & 15;
      int sc = cc ^ (row & 15);
      GLD16(Vb + (size_t)row * NX + kt * 128 + sc * 8,
            sV[p] + ((size_t)it * 256 + wv * 64) * 8);
    }
  };

  bf16x8 qa[2];
#pragma unroll
  for (int kk = 0; kk < 2; ++kk)
    qa[kk] = *(const bf16x8*)&Qb[(wv * 16 + lr) * DH + kk * 32 + lh * 8];

  float lp[4] = {0.f, 0.f, 0.f, 0.f};
  f32x4 zero4 = {0.f, 0.f, 0.f, 0.f};
  f32x4 accp[4];
#pragma unroll
  for (int d = 0; d < 4; ++d) accp[d] = zero4;

  stageKV(0, 0);  // prologue

  for (int kt = 0; kt < 16; ++kt) {
    const int p = kt & 1;
    if (kt < 15) {
      stageKV(kt + 1, p ^ 1);
      asm volatile("s_waitcnt vmcnt(8)" ::: "memory");
    } else {
      asm volatile("s_waitcnt vmcnt(0)" ::: "memory");
    }
    __builtin_amdgcn_s_barrier();  // tile kt's K/V visible to all waves
    __builtin_amdgcn_s_setprio(1);
#pragma unroll
    for (int n = 0; n < 8; ++n) {
      f32x4 a4 = {0.f, 0.f, 0.f, 0.f};
      int r = n * 16 + lr;
#pragma unroll
      for (int kk = 0; kk < 2; ++kk) {
        bf16x8 kb =
            *(const bf16x8*)&sK[p][r * 64 + (((kk * 4 + lh) ^ (r & 7)) << 3)];
        a4 = __builtin_amdgcn_mfma_f32_16x16x32_bf16(qa[kk], kb, a4, 0, 0, 0);
      }
      __builtin_amdgcn_s_setprio(0);
#pragma unroll
      for (int j = 0; j < 4; ++j) {
        float e = exp2_fast(a4[j]);  // scores already in log2 units
        lp[j] += e;
        int qr = wv * 16 + lh * 4 + j;
        int key = n * 16 + lr;
        int idx = qr * 128 + ((((key >> 3) ^ (qr & 15))) << 3) + (key & 7);
        sPe[idx] = (__bf16)e;
      }
      __builtin_amdgcn_s_setprio(1);
    }
    __builtin_amdgcn_s_setprio(0);
    // sPe is wave-private: wave-local ordering only (no block barrier).
    asm volatile("s_waitcnt lgkmcnt(0)" ::: "memory");
    __builtin_amdgcn_sched_barrier(0);
    const int prow = wv * 16 + lr;
    __builtin_amdgcn_s_setprio(1);
#pragma unroll
    for (int kk = 0; kk < 4; ++kk) {
      int pidx = prow * 128 + (((kk * 4 + lh) ^ (prow & 15)) << 3);
      bf16x8 pe = *(const bf16x8*)&sPe[pidx];
#pragma unroll
      for (int df = 0; df < 4; ++df) {
        int vr = df * 16 + lr;
        bf16x8 vb =
            *(const bf16x8*)&sV[p][vr * 128 + (((kk * 4 + lh) ^ (vr & 15)) << 3)];
        accp[df] = __builtin_amdgcn_mfma_f32_16x16x32_bf16(pe, vb, accp[df], 0, 0, 0);
      }
    }
    __builtin_amdgcn_s_setprio(0);
    asm volatile("s_waitcnt lgkmcnt(0)" ::: "memory");
    __builtin_amdgcn_s_barrier();  // all waves done reading buf p before restage
  }
#pragma unroll
  for (int off = 1; off < 16; off <<= 1)
#pragma unroll
    for (int j = 0; j < 4; ++j) lp[j] += __shfl_xor(lp[j], off, 64);

  const int b = bh >> 4, h = bh & 15;
  const float c1 = w / ((float)NX + g);
  const float c2 = w * g / ((float)NX + g) + (1.f - w);
  float rl[4];
#pragma unroll
  for (int j = 0; j < 4; ++j) rl[j] = 1.f / lp[j];
#pragma unroll
  for (int df = 0; df < 4; ++df) {
    int d = df * 16 + lr;
    float cv = vcs[bh * DH + d];
#pragma unroll
    for (int j = 0; j < 4; ++j) {
      int qr = q0 + wv * 16 + lh * 4 + j;
      float p = accp[df][j] * rl[j];
      ctxh[(((size_t)b * NQ + qr) * NH + h) * DH + d] = f2bf(c1 * cv + c2 * p);
    }
  }
}

// ---------------- launch ----------------

extern "C" void kernel_launch(void* const* d_in, const int* in_sizes, int n_in,
                              void* d_out, int out_size, void* d_ws,
                              size_t ws_size, hipStream_t stream) {
  const float* x = (const float*)d_in[0];
  const float* cls = (const float*)d_in[1];
  const float* w_kv = (const float*)d_in[2];
  const float* w_q = (const float*)d_in[3];
  const float* w_la = (const float*)d_in[4];
  const float* w_proj = (const float*)d_in[5];
  const float* b_proj = (const float*)d_in[6];
  const float* att_w = (const float*)d_in[7];
  float* out = (float*)d_out;

  char* ws = (char*)d_ws;
  size_t off = 0;
  auto alloc = [&](size_t bytes) {
    void* p = ws + off;
    off += (bytes + 255) & ~(size_t)255;
    return p;
  };
  uint16_t* xh = (uint16_t*)alloc(4ull * NX * CDIM * 2);
  uint16_t* ch = (uint16_t*)alloc(4ull * NQ * CDIM * 2);
  uint16_t* wkvT = (uint16_t*)alloc(2048ull * 1024 * 2);
  uint16_t* wqT = (uint16_t*)alloc(1024ull * 1024 * 2);
  uint16_t* wpT = (uint16_t*)alloc(1024ull * 1024 * 2);
  uint16_t* kbf = (uint16_t*)alloc(4ull * NH * NX * DH * 2);
  uint16_t* vT = (uint16_t*)alloc(4ull * NH * DH * NX * 2);
  uint16_t* qbf = (uint16_t*)alloc(4ull * NH * NQ * DH * 2);
  float* gv = (float*)alloc(4ull * NH * NX * 4);
  float* gate = (float*)alloc(1024);
  float* vcs = (float*)alloc(4ull * NH * DH * 4);
  uint16_t* ctxh = (uint16_t*)alloc(4ull * NQ * CDIM * 2);

  prep_kernel<<<3584, 256, 0, stream>>>(x, xh, cls, ch, w_kv, wkvT, w_q, wqT,
                                        w_proj, wpT);

  aux_mm_kernel<<<384, 256, 0, stream>>>(ch, wqT, qbf, xh, w_la, gv);
  gemm_kv8<<<dim3(32, 8), 512, 0, stream>>>(xh, wkvT, kbf, vT);

  gatev_kernel<<<320, 256, 0, stream>>>(gv, gate, vT, vcs);

  attn_kernel<<<dim3(64, 8), 256, 0, stream>>>(qbf, kbf, vT, gate, att_w, vcs, ctxh);

  gemm_proj<<<dim3(32, 8), 256, 0, stream>>>(ctxh, wpT, out, b_proj);
}